// Round 2
// baseline (3066.893 us; speedup 1.0000x reference)
//
#include <hip/hip_runtime.h>
#include <hip/hip_bf16.h>

#define DEV __device__ __forceinline__

// ---------------- problem constants (fixed by setup_inputs) ----------------
constexpr int Nn   = 65536;        // num_ent
constexpr int Ee   = 262144;       // edges
constexpr int Rr   = 200;          // relation_num
constexpr int BQ   = 40;           // batch queries
constexpr int Rt   = Rr * BQ;      // 8000
constexpr int Hh   = 64;
constexpr int SHOT = 5;
constexpr float SLOPE  = 0.22916667f;   // (1/8 + 1/3)/2
constexpr float EPS_LN = 1e-5f;

// ---------------- workspace layout (float offsets); ws[0..15] = flag block ----
constexpr size_t BASE = 16;
constexpr size_t off_node   = BASE;
constexpr size_t off_node2  = off_node  + (size_t)Nn*Hh;
constexpr size_t off_rel    = off_node2 + (size_t)Nn*Hh;
constexpr size_t off_rel2   = off_rel   + (size_t)Rt*Hh;
constexpr size_t off_fin    = off_rel2  + (size_t)Rt*Hh;      // 3 slabs of Rt*Hh
constexpr size_t off_finln  = off_fin   + (size_t)3*Rt*Hh;
constexpr size_t off_loop   = off_finln + (size_t)Rt*Hh;
constexpr size_t off_av     = off_loop  + (size_t)BQ*Hh;
constexpr size_t off_bvv    = off_av    + (size_t)Ee;
constexpr size_t off_asum   = off_bvv   + (size_t)Ee;
constexpr size_t off_bsum   = off_asum  + (size_t)Nn;
constexpr size_t off_deg    = off_bsum  + (size_t)Rt;
constexpr size_t off_Wmsg   = off_deg   + (size_t)Nn;
constexpr size_t off_Wht2r  = off_Wmsg  + (size_t)3*192*64;
constexpr size_t off_Went   = off_Wht2r + (size_t)3*192*64;
constexpr size_t off_Wrel   = off_Went  + (size_t)3*64*64;
constexpr size_t off_Wfin   = off_Wrel  + (size_t)3*64*64;
constexpr size_t off_Wloop  = off_Wfin  + (size_t)192*64;
constexpr size_t off_bmsg   = off_Wloop + (size_t)3*128*64;
constexpr size_t off_bht2r  = off_bmsg  + 192;
constexpr size_t off_bent   = off_bht2r + 192;
constexpr size_t off_brel   = off_bent  + 192;
constexpr size_t off_bloop  = off_brel  + 192;
constexpr size_t off_bfin   = off_bloop + 192;
constexpr size_t off_Wa     = off_bfin  + 64;
constexpr size_t off_ba     = off_Wa    + 384;
constexpr size_t off_Wb     = off_ba    + 4;
constexpr size_t off_bb     = off_Wb    + 384;
constexpr size_t off_pos    = off_bb    + 4;
constexpr size_t off_srel   = off_pos   + 1024;
constexpr size_t off_loop0  = off_srel  + 64;
constexpr size_t off_end    = off_loop0 + 64;

DEV float bf2f(unsigned short u) { return __uint_as_float(((unsigned)u) << 16); }
DEV float actf(float x) { return x >= 0.f ? x : x * SLOPE; }
DEV void atomAddF(float* p, float v) {
#if defined(__HIP_DEVICE_COMPILE__)
    unsafeAtomicAdd(p, v);   // native global_atomic_add_f32; d_ws is coarse-grained
#endif
}
// dtype-adaptive load of float input i (isb=1: bf16 halves, isb=0: plain f32)
DEV float loadF(const void* p, size_t i, int isb) {
    return isb ? bf2f(((const unsigned short*)p)[i]) : ((const float*)p)[i];
}

// ============================ dtype sniff ============================
// Reads first 64 half-words of pos_emb as bf16. Genuine bf16 N(0,0.05) data is
// all tame; an fp32 buffer's low half-words have random exponents -> almost
// surely at least one |x|>1e3 or NaN/inf among 32 samples.
__global__ __launch_bounds__(64) void k_sniff(const unsigned short* __restrict__ pos, int* __restrict__ flag) {
    float v = bf2f(pos[threadIdx.x]);
    bool bad = !(fabsf(v) < 1e3f);          // catches huge, inf, NaN
    unsigned long long m = __ballot(bad);
    if (threadIdx.x == 0) flag[0] = (m == 0ull) ? 1 : 0;   // 1 = bf16, 0 = f32
}

__global__ __launch_bounds__(256) void k_fill16(unsigned short* __restrict__ out, int n, unsigned short val) {
    int i = blockIdx.x * 256 + threadIdx.x;
    if (i < n) out[i] = val;
}

// ============================ weight prep ============================
struct PrepArgs { const void* src[19]; float* dst[19]; };

__global__ __launch_bounds__(256) void k_prep(PrepArgs a, const int* __restrict__ flag) {
    // jobs 0..4: wave-sliced transpose dst[b][wv][k][hh] = W[b][wv*16+hh][k]
    // job  5  : plain transpose dst[b][k][h] = W[b][h][k]  (K=128)
    // jobs 6..18: elementwise copy/convert
    constexpr int NJ = 19;
    constexpr int type[NJ] = {1,1,1,1,1,2, 0,0,0,0,0,0,0,0,0,0,0,0,0};
    constexpr int KD[NJ]   = {192,192,64,64,192,128, 0,0,0,0,0,0,0,0,0,0,0,0,0};
    constexpr int NEL[NJ]  = {36864,36864,12288,12288,12288,24576,
                              192,192,192,192,192,64,384,3,384,3,1024,64,64};
    const int isb = flag[0];
    int tid0 = blockIdx.x * blockDim.x + threadIdx.x;
    int stride = gridDim.x * blockDim.x;
    for (int j = 0; j < NJ; ++j) {
        const void* s = a.src[j];
        float* d = a.dst[j];
        int n = NEL[j];
        if (type[j] == 0) {
            for (int i = tid0; i < n; i += stride) d[i] = loadF(s, i, isb);
        } else if (type[j] == 1) {
            int K = KD[j];
            for (int i = tid0; i < n; i += stride) {
                int hh = i & 15;
                int k  = (i >> 4) % K;
                int rest = i / (16 * K);      // b*4 + wv
                int wv = rest & 3, b = rest >> 2;
                d[i] = loadF(s, (size_t)(b*64 + wv*16 + hh) * K + k, isb);
            }
        } else {
            int K = KD[j];
            for (int i = tid0; i < n; i += stride) {
                int h = i & 63;
                int k = (i >> 6) % K;
                int b = i / (64 * K);
                d[i] = loadF(s, (size_t)(b*64 + h) * K + k, isb);
            }
        }
    }
}

// ============================ init kernels ============================
__global__ __launch_bounds__(256) void k_count_deg(const int* __restrict__ rowp, float* __restrict__ deg) {
    int e = blockIdx.x * 256 + threadIdx.x;
    if (e < Ee) atomAddF(&deg[rowp[e]], 1.0f);
}
__global__ __launch_bounds__(256) void k_deg_inv(float* __restrict__ deg) {
    int n = blockIdx.x * 256 + threadIdx.x;
    if (n < Nn) { float d = deg[n]; deg[n] = d > 0.f ? 1.0f / sqrtf(d) : 0.0f; }
}
__global__ __launch_bounds__(256) void k_node_init(const int* __restrict__ labels,
                                                   const float* __restrict__ posf,
                                                   float* __restrict__ node) {
    int idx = blockIdx.x * 256 + threadIdx.x;
    if (idx >= Nn * Hh) return;
    int n = idx >> 6, h = idx & 63;
    int pos = labels[2*n] * 4 + labels[2*n + 1];
    node[idx] = posf[pos * 64 + h];
}
__global__ __launch_bounds__(256) void k_set_rows(const int* __restrict__ positions,
                                                  const float* __restrict__ srcrow,
                                                  float* __restrict__ node) {
    int idx = blockIdx.x * 256 + threadIdx.x;
    if (idx >= BQ * Hh) return;
    int b = idx >> 6, h = idx & 63;
    node[(size_t)positions[b] * 64 + h] = srcrow[h];
}
__global__ __launch_bounds__(256) void k_rel_init(const int* __restrict__ qrel,
                                                  const float* __restrict__ srel,
                                                  float* __restrict__ rel) {
    int idx = blockIdx.x * 256 + threadIdx.x;
    if (idx >= BQ * Hh) return;
    int b = idx >> 6, h = idx & 63;
    rel[((size_t)qrel[b] + (size_t)b * Rr) * 64 + h] = srel[h];
}
__global__ __launch_bounds__(256) void k_loop_init(const float* __restrict__ l0, float* __restrict__ loop) {
    int idx = blockIdx.x * 256 + threadIdx.x;
    if (idx < BQ * Hh) loop[idx] = l0[idx & 63];
}

// ============================ alpha/beta pass ============================
__global__ __launch_bounds__(256) void k_ab(const float* __restrict__ rel,
                                            const int* __restrict__ et, const int* __restrict__ eqr,
                                            const int* __restrict__ rowp,
                                            const float* __restrict__ Wa, const float* __restrict__ ba,
                                            const float* __restrict__ Wb, const float* __restrict__ bb,
                                            float* __restrict__ a_vals, float* __restrict__ b_vals,
                                            float* __restrict__ a_sum, float* __restrict__ b_sum) {
    int tid = threadIdx.x, lane = tid & 63, wv = tid >> 6;
    int e = blockIdx.x * 4 + wv;
    int t = et[e], q = eqr[e];
    float r  = rel[(size_t)t * 64 + lane];
    float qv = rel[(size_t)q * 64 + lane];
    float pa = actf(r) * Wa[lane] + actf(qv) * Wa[64 + lane];
    float pb = r * Wb[lane] + qv * Wb[64 + lane];
    for (int off = 32; off; off >>= 1) { pa += __shfl_xor(pa, off); pb += __shfl_xor(pb, off); }
    if (lane == 0) {
        float av = expf(pa + ba[0]);
        float bv = expf(pb + bb[0]);
        a_vals[e] = av; b_vals[e] = bv;
        atomAddF(&a_sum[rowp[e]], av);
        atomAddF(&b_sum[t], bv);
    }
}

// ============================ edge message GEMM kernels ============================
// one block = 64 edges; feat staged transposed in LDS (stride 65 -> conflict free);
// wave wv computes output columns [wv*16, wv*16+16) with wave-uniform loads of W.
__global__ __launch_bounds__(256) void k_msg1(const float* __restrict__ node, const float* __restrict__ rel,
                                              const int* __restrict__ col, const int* __restrict__ rowp,
                                              const int* __restrict__ et, const int* __restrict__ eqr,
                                              const float* __restrict__ Wv,    // [4][192][16]
                                              const float* __restrict__ bias,  // [64]
                                              const float* __restrict__ a_vals, const float* __restrict__ a_sum,
                                              const float* __restrict__ deg_inv,
                                              float* __restrict__ node_new) {
    __shared__ float featT[192 * 65];
    __shared__ int s_col[64], s_row[64], s_et[64], s_eqr[64];
    __shared__ float s_coeff[64];
    const int tid = threadIdx.x;
    const int lane = tid & 63;
    const int wv = tid >> 6;
    const int e0 = blockIdx.x * 64;
    if (tid < 64) {
        int e = e0 + tid;
        int c = col[e], r = rowp[e];
        s_col[tid] = c; s_row[tid] = r; s_et[tid] = et[e]; s_eqr[tid] = eqr[e];
        int rr = rowp[r];                               // faithful double index
        float dn = deg_inv[r] * deg_inv[c];
        s_coeff[tid] = a_vals[e] / (a_sum[rr] + 1e-10f) * dn * dn;  // ent_norm applied twice
    }
    __syncthreads();
    for (int j = wv; j < 192; j += 4) {
        int e = j / 3, part = j - e * 3;
        int srow = part == 0 ? s_col[e] : (part == 1 ? s_et[e] : s_eqr[e]);
        const float* base = part == 0 ? node : rel;
        featT[(part * 64 + lane) * 65 + e] = base[(size_t)srow * 64 + lane];
    }
    __syncthreads();
    float acc[16];
#pragma unroll
    for (int h = 0; h < 16; ++h) acc[h] = 0.f;
    const float* Wl = Wv + wv * (192 * 16);
    for (int k = 0; k < 192; ++k) {
        float f = featT[k * 65 + lane];
        const float* wr = Wl + k * 16;
#pragma unroll
        for (int hh = 0; hh < 16; ++hh) acc[hh] = fmaf(f, wr[hh], acc[hh]);
    }
    __syncthreads();
    float* msgT = featT;   // reuse LDS (sync above/below guards the aliasing)
    float cf = s_coeff[lane];
#pragma unroll
    for (int hh = 0; hh < 16; ++hh) {
        int h = wv * 16 + hh;
        msgT[h * 65 + lane] = actf(acc[hh] + bias[h]) * cf;
    }
    __syncthreads();
    for (int ee = 0; ee < 16; ++ee) {
        int e = wv * 16 + ee;
        atomAddF(&node_new[(size_t)s_row[e] * 64 + lane], msgT[lane * 65 + e]);
    }
}

__global__ __launch_bounds__(256) void k_msg2(const float* __restrict__ node, const float* __restrict__ rel,
                                              const int* __restrict__ col, const int* __restrict__ rowp,
                                              const int* __restrict__ et, const int* __restrict__ eqr,
                                              const float* __restrict__ Wv, const float* __restrict__ bias,
                                              const float* __restrict__ b_vals, const float* __restrict__ b_sum,
                                              float* __restrict__ rel_new) {
    __shared__ float featT[192 * 65];
    __shared__ int s_col[64], s_row[64], s_et[64], s_eqr[64];
    __shared__ float s_coeff[64];
    const int tid = threadIdx.x;
    const int lane = tid & 63;
    const int wv = tid >> 6;
    const int e0 = blockIdx.x * 64;
    if (tid < 64) {
        int e = e0 + tid;
        s_col[tid] = col[e]; s_row[tid] = rowp[e];
        int t = et[e];
        s_et[tid] = t; s_eqr[tid] = eqr[e];
        int tt = et[t];                                 // faithful double index
        s_coeff[tid] = b_vals[e] / (b_sum[tt] + 1e-10f);
    }
    __syncthreads();
    for (int j = wv; j < 192; j += 4) {
        int e = j / 3, part = j - e * 3;
        int srow = part == 0 ? s_col[e] : (part == 1 ? s_row[e] : s_eqr[e]);
        const float* base = part == 2 ? rel : node;
        featT[(part * 64 + lane) * 65 + e] = base[(size_t)srow * 64 + lane];
    }
    __syncthreads();
    float acc[16];
#pragma unroll
    for (int h = 0; h < 16; ++h) acc[h] = 0.f;
    const float* Wl = Wv + wv * (192 * 16);
    for (int k = 0; k < 192; ++k) {
        float f = featT[k * 65 + lane];
        const float* wr = Wl + k * 16;
#pragma unroll
        for (int hh = 0; hh < 16; ++hh) acc[hh] = fmaf(f, wr[hh], acc[hh]);
    }
    __syncthreads();
    float* msgT = featT;
    float cf = s_coeff[lane];
#pragma unroll
    for (int hh = 0; hh < 16; ++hh) {
        int h = wv * 16 + hh;
        msgT[h * 65 + lane] = actf(acc[hh] + bias[h]) * cf;
    }
    __syncthreads();
    for (int ee = 0; ee < 16; ++ee) {
        int e = wv * 16 + ee;
        atomAddF(&rel_new[(size_t)s_et[e] * 64 + lane], msgT[lane * 65 + e]);
    }
}

// ============================ row-wise 64x64 transform + LN ============================
__global__ __launch_bounds__(256) void k_ent_ln(const float* __restrict__ x,    // node_new
                                                const float* __restrict__ Wv,   // [4][64][16]
                                                const float* __restrict__ bias,
                                                float* __restrict__ out) {      // node_emb
    __shared__ float xT[64 * 65];
    int tid = threadIdx.x, lane = tid & 63;
    int wv = tid >> 6;
    size_t n0 = (size_t)blockIdx.x * 64;
    for (int j = wv; j < 64; j += 4) xT[lane * 65 + j] = x[(n0 + j) * 64 + lane];
    __syncthreads();
    float acc[16];
#pragma unroll
    for (int h = 0; h < 16; ++h) acc[h] = 0.f;
    const float* Wl = Wv + wv * (64 * 16);
    for (int k = 0; k < 64; ++k) {
        float f = xT[k * 65 + lane];
        const float* wr = Wl + k * 16;
#pragma unroll
        for (int hh = 0; hh < 16; ++hh) acc[hh] = fmaf(f, wr[hh], acc[hh]);
    }
    __syncthreads();
    float* yT = xT;
#pragma unroll
    for (int hh = 0; hh < 16; ++hh) {
        int h = wv * 16 + hh;
        yT[h * 65 + lane] = actf(acc[hh] + bias[h]);
    }
    __syncthreads();
    for (int jj = 0; jj < 16; ++jj) {
        int j = wv * 16 + jj;
        float v = yT[lane * 65 + j];
        float s = v, s2 = v * v;
        for (int off = 32; off; off >>= 1) { s += __shfl_xor(s, off); s2 += __shfl_xor(s2, off); }
        float mean = s * (1.f / 64.f);
        float var = s2 * (1.f / 64.f) - mean * mean;
        if (var < 0.f) var = 0.f;
        out[(n0 + j) * 64 + lane] = (v - mean) / sqrtf(var + EPS_LN);
    }
}

__global__ __launch_bounds__(256) void k_rel_ln(const float* __restrict__ x,    // rel_new (agg)
                                                const float* __restrict__ Wv, const float* __restrict__ bias,
                                                float* __restrict__ rel,        // in-place update
                                                float* __restrict__ fin_i) {    // finals[i]
    __shared__ float xT[64 * 65];
    int tid = threadIdx.x, lane = tid & 63;
    int wv = tid >> 6;
    size_t r0 = (size_t)blockIdx.x * 64;
    for (int j = wv; j < 64; j += 4) xT[lane * 65 + j] = x[(r0 + j) * 64 + lane];
    __syncthreads();
    float acc[16];
#pragma unroll
    for (int h = 0; h < 16; ++h) acc[h] = 0.f;
    const float* Wl = Wv + wv * (64 * 16);
    for (int k = 0; k < 64; ++k) {
        float f = xT[k * 65 + lane];
        const float* wr = Wl + k * 16;
#pragma unroll
        for (int hh = 0; hh < 16; ++hh) acc[hh] = fmaf(f, wr[hh], acc[hh]);
    }
    __syncthreads();
    float* yT = xT;
#pragma unroll
    for (int hh = 0; hh < 16; ++hh) {
        int h = wv * 16 + hh;
        yT[h * 65 + lane] = actf(acc[hh] + bias[h]);
    }
    __syncthreads();
    for (int jj = 0; jj < 16; ++jj) {
        int j = wv * 16 + jj;
        float v = yT[lane * 65 + j] + rel[(r0 + j) * 64 + lane];   // residual
        float s = v, s2 = v * v;
        for (int off = 32; off; off >>= 1) { s += __shfl_xor(s, off); s2 += __shfl_xor(s2, off); }
        float mean = s * (1.f / 64.f);
        float var = s2 * (1.f / 64.f) - mean * mean;
        if (var < 0.f) var = 0.f;
        float nv = (v - mean) / sqrtf(var + EPS_LN);
        rel[(r0 + j) * 64 + lane] = nv;
        fin_i[(r0 + j) * 64 + lane] = nv;
    }
}

__global__ __launch_bounds__(64) void k_loop_upd(const float* __restrict__ rel, const int* __restrict__ qrel,
                                                 const float* __restrict__ Wt,   // [128][64] plain transposed
                                                 const float* __restrict__ bias,
                                                 float* __restrict__ loop) {
    __shared__ float cat[128];
    int b = blockIdx.x, lane = threadIdx.x;
    float lv = loop[b * 64 + lane];
    int qr = qrel[b] + b * Rr;
    cat[lane] = lv;
    cat[64 + lane] = rel[(size_t)qr * 64 + lane];
    __syncthreads();
    float acc = 0.f;
    for (int k = 0; k < 128; ++k) acc = fmaf(cat[k], Wt[k * 64 + lane], acc);
    float v = lv + actf(acc + bias[lane]);
    float s = v, s2 = v * v;
    for (int off = 32; off; off >>= 1) { s += __shfl_xor(s, off); s2 += __shfl_xor(s2, off); }
    float mean = s * (1.f / 64.f);
    float var = s2 * (1.f / 64.f) - mean * mean;
    if (var < 0.f) var = 0.f;
    loop[b * 64 + lane] = (v - mean) / sqrtf(var + EPS_LN);
}

// ============================ final projection + LN ============================
__global__ __launch_bounds__(256) void k_final(const float* __restrict__ finals,  // [3][Rt][64]
                                               const float* __restrict__ Wv,      // [4][192][16]
                                               const float* __restrict__ bias,
                                               float* __restrict__ fin_ln) {
    __shared__ float featT[192 * 65];
    int tid = threadIdx.x, lane = tid & 63;
    int wv = tid >> 6;
    size_t r0 = (size_t)blockIdx.x * 64;
    for (int j = wv; j < 192; j += 4) {
        int e = j / 3, part = j - e * 3;
        featT[(part * 64 + lane) * 65 + e] = finals[(size_t)part * Rt * 64 + (r0 + e) * 64 + lane];
    }
    __syncthreads();
    float acc[16];
#pragma unroll
    for (int h = 0; h < 16; ++h) acc[h] = 0.f;
    const float* Wl = Wv + wv * (192 * 16);
    for (int k = 0; k < 192; ++k) {
        float f = featT[k * 65 + lane];
        const float* wr = Wl + k * 16;
#pragma unroll
        for (int hh = 0; hh < 16; ++hh) acc[hh] = fmaf(f, wr[hh], acc[hh]);
    }
    __syncthreads();
    float* yT = featT;
#pragma unroll
    for (int hh = 0; hh < 16; ++hh) {
        int h = wv * 16 + hh;
        yT[h * 65 + lane] = actf(acc[hh] + bias[h]);
    }
    __syncthreads();
    for (int jj = 0; jj < 16; ++jj) {
        int j = wv * 16 + jj;
        float v = yT[lane * 65 + j];
        float s = v, s2 = v * v;
        for (int off = 32; off; off >>= 1) { s += __shfl_xor(s, off); s2 += __shfl_xor(s2, off); }
        float mean = s * (1.f / 64.f);
        float var = s2 * (1.f / 64.f) - mean * mean;
        if (var < 0.f) var = 0.f;
        fin_ln[(r0 + j) * 64 + lane] = (v - mean) / sqrtf(var + EPS_LN);
    }
}

__global__ __launch_bounds__(256) void k_out(const float* __restrict__ fin_ln,
                                             const float* __restrict__ loop,
                                             void* __restrict__ out, int n,
                                             const int* __restrict__ flag) {
    int idx = blockIdx.x * 256 + threadIdx.x;
    if (idx >= n) return;
    int h = idx & 63;
    int j = (idx >> 6) % (Rr + 1);
    int g = idx / ((Rr + 1) * 64);
    float v = 0.f;
    if (j < Rr) {
        for (int s = 0; s < SHOT; ++s)
            v += fin_ln[(size_t)((g * SHOT + s) * Rr + j) * 64 + h];
    } else {
        for (int s = 0; s < SHOT; ++s)
            v += loop[(g * SHOT + s) * 64 + h];
    }
    v *= (1.0f / SHOT);
    if (flag[0]) ((__hip_bfloat16*)out)[idx] = __float2bfloat16(v);
    else         ((float*)out)[idx] = v;
}

// ============================ host launch ============================
extern "C" void kernel_launch(void* const* d_in, const int* in_sizes, int n_in,
                              void* d_out, int out_size, void* d_ws, size_t ws_size,
                              hipStream_t stream) {
    // sentinel guards: absmax ~123 => ws too small; ~77 => wrong input count
    if (ws_size < off_end * 4 || n_in != 29) {
        k_fill16<<<(out_size + 255) / 256, 256, 0, stream>>>(
            (unsigned short*)d_out, out_size, (n_in != 29) ? (unsigned short)0x429A : (unsigned short)0x42F6);
        return;
    }

    const int* edge_index = (const int*)d_in[0];
    const int* col  = edge_index;          // edge_index[0] (h side)
    const int* rowp = edge_index + Ee;     // edge_index[1] (t side)
    const int* et   = (const int*)d_in[1];
    const int* eqr  = (const int*)d_in[2];
    const int* hpos = (const int*)d_in[3];
    const int* tpos = (const int*)d_in[4];
    const int* qrel = (const int*)d_in[5];
    const int* labels = (const int*)d_in[6];

    float* W = (float*)d_ws;
    int*   flag  = (int*)d_ws;             // ws[0]
    float* node  = W + off_node;
    float* node2 = W + off_node2;
    float* rel   = W + off_rel;
    float* rel2  = W + off_rel2;
    float* fin   = W + off_fin;
    float* finln = W + off_finln;
    float* loop  = W + off_loop;
    float* av    = W + off_av;
    float* bvv   = W + off_bvv;
    float* asum  = W + off_asum;
    float* bsum  = W + off_bsum;
    float* deg   = W + off_deg;

    // --- dtype sniff then weight prep ---
    k_sniff<<<1, 64, 0, stream>>>((const unsigned short*)d_in[10], flag);
    PrepArgs pa;
    const int src_idx[19] = {13,15,23,25,27,21, 14,16,24,26,22,28,17,18,19,20,10,11,12};
    float* dsts[19] = {W+off_Wmsg, W+off_Wht2r, W+off_Went, W+off_Wrel, W+off_Wfin, W+off_Wloop,
                       W+off_bmsg, W+off_bht2r, W+off_bent, W+off_brel, W+off_bloop, W+off_bfin,
                       W+off_Wa, W+off_ba, W+off_Wb, W+off_bb, W+off_pos, W+off_srel, W+off_loop0};
    for (int j = 0; j < 19; ++j) { pa.src[j] = d_in[src_idx[j]]; pa.dst[j] = dsts[j]; }
    k_prep<<<144, 256, 0, stream>>>(pa, flag);

    // --- degree / init ---
    (void)hipMemsetAsync(deg, 0, (size_t)Nn * 4, stream);
    k_count_deg<<<Ee / 256, 256, 0, stream>>>(rowp, deg);
    k_deg_inv<<<Nn / 256, 256, 0, stream>>>(deg);
    k_node_init<<<(Nn * Hh) / 256, 256, 0, stream>>>(labels, W + off_pos, node);
    k_set_rows<<<(BQ * Hh + 255) / 256, 256, 0, stream>>>(hpos, W + off_pos, node);        // pos_emb[0]
    k_set_rows<<<(BQ * Hh + 255) / 256, 256, 0, stream>>>(tpos, W + off_pos + 64, node);   // pos_emb[1]
    (void)hipMemsetAsync(rel, 0, (size_t)Rt * Hh * 4, stream);
    k_rel_init<<<(BQ * Hh + 255) / 256, 256, 0, stream>>>(qrel, W + off_srel, rel);
    k_loop_init<<<(BQ * Hh + 255) / 256, 256, 0, stream>>>(W + off_loop0, loop);

    // --- layers ---
    for (int i = 0; i < 3; ++i) {
        (void)hipMemsetAsync(asum, 0, (size_t)Nn * 4, stream);
        (void)hipMemsetAsync(bsum, 0, (size_t)Rt * 4, stream);
        k_ab<<<Ee / 4, 256, 0, stream>>>(rel, et, eqr, rowp,
                                         W + off_Wa + i * 128, W + off_ba + i,
                                         W + off_Wb + i * 128, W + off_bb + i,
                                         av, bvv, asum, bsum);
        (void)hipMemsetAsync(node2, 0, (size_t)Nn * Hh * 4, stream);
        k_msg1<<<Ee / 64, 256, 0, stream>>>(node, rel, col, rowp, et, eqr,
                                            W + off_Wmsg + (size_t)i * 12288, W + off_bmsg + i * 64,
                                            av, asum, deg, node2);
        k_ent_ln<<<Nn / 64, 256, 0, stream>>>(node2, W + off_Went + (size_t)i * 4096,
                                              W + off_bent + i * 64, node);
        (void)hipMemsetAsync(rel2, 0, (size_t)Rt * Hh * 4, stream);
        k_msg2<<<Ee / 64, 256, 0, stream>>>(node, rel, col, rowp, et, eqr,
                                            W + off_Wht2r + (size_t)i * 12288, W + off_bht2r + i * 64,
                                            bvv, bsum, rel2);
        k_rel_ln<<<Rt / 64, 256, 0, stream>>>(rel2, W + off_Wrel + (size_t)i * 4096,
                                              W + off_brel + i * 64, rel, fin + (size_t)i * Rt * Hh);
        k_loop_upd<<<BQ, 64, 0, stream>>>(rel, qrel, W + off_Wloop + (size_t)i * 8192,
                                          W + off_bloop + i * 64, loop);
    }

    // --- final projection, LN, shot-mean, output ---
    k_final<<<Rt / 64, 256, 0, stream>>>(fin, W + off_Wfin, W + off_bfin, finln);
    k_out<<<(out_size + 255) / 256, 256, 0, stream>>>(finln, loop, d_out, out_size, flag);
}

// Round 3
// 1071.201 us; speedup vs baseline: 2.8630x; 2.8630x over previous
//
#include <hip/hip_runtime.h>
#include <hip/hip_bf16.h>

#define DEV __device__ __forceinline__

// ---------------- problem constants (fixed by setup_inputs) ----------------
constexpr int Nn   = 65536;        // num_ent
constexpr int Ee   = 262144;       // edges
constexpr int Rr   = 200;          // relation_num
constexpr int BQ   = 40;           // batch queries
constexpr int Rt   = Rr * BQ;      // 8000
constexpr int Hh   = 64;
constexpr int SHOT = 5;
constexpr float SLOPE  = 0.22916667f;   // (1/8 + 1/3)/2
constexpr float EPS_LN = 1e-5f;

// ---------------- workspace layout (float offsets); ws[0..15] = flag block ----
constexpr size_t BASE = 16;
constexpr size_t off_node   = BASE;
constexpr size_t off_node2  = off_node  + (size_t)Nn*Hh;
constexpr size_t off_rel    = off_node2 + (size_t)Nn*Hh;
constexpr size_t off_rel2   = off_rel   + (size_t)Rt*Hh;
constexpr size_t off_fin    = off_rel2  + (size_t)Rt*Hh;      // 3 slabs of Rt*Hh
constexpr size_t off_finln  = off_fin   + (size_t)3*Rt*Hh;
constexpr size_t off_loop   = off_finln + (size_t)Rt*Hh;
constexpr size_t off_av     = off_loop  + (size_t)BQ*Hh;
constexpr size_t off_bvv    = off_av    + (size_t)Ee;
constexpr size_t off_asum   = off_bvv   + (size_t)Ee;
constexpr size_t off_bsum   = off_asum  + (size_t)Nn;
constexpr size_t off_deg    = off_bsum  + (size_t)Rt;
constexpr size_t off_Went   = off_deg   + (size_t)Nn;
constexpr size_t off_Wrel   = off_Went  + (size_t)3*64*64;
constexpr size_t off_Wfin   = off_Wrel  + (size_t)3*64*64;
constexpr size_t off_Wloop  = off_Wfin  + (size_t)192*64;
constexpr size_t off_bmsg   = off_Wloop + (size_t)3*128*64;
constexpr size_t off_bht2r  = off_bmsg  + 192;
constexpr size_t off_bent   = off_bht2r + 192;
constexpr size_t off_brel   = off_bent  + 192;
constexpr size_t off_bloop  = off_brel  + 192;
constexpr size_t off_bfin   = off_bloop + 192;
constexpr size_t off_Wa     = off_bfin  + 64;
constexpr size_t off_ba     = off_Wa    + 384;
constexpr size_t off_Wb     = off_ba    + 4;
constexpr size_t off_bb     = off_Wb    + 384;
constexpr size_t off_pos    = off_bb    + 4;
constexpr size_t off_srel   = off_pos   + 1024;
constexpr size_t off_loop0  = off_srel  + 64;
// bf16 fragment-packed msg weights (each: 3 layers x 12288 u16 = 18432 floats)
constexpr size_t off_WmsgF  = off_loop0 + 64;
constexpr size_t off_Wht2rF = off_WmsgF + 18432;
constexpr size_t off_end    = off_Wht2rF + 18432;

typedef __attribute__((ext_vector_type(8))) short short8v;
typedef __attribute__((ext_vector_type(4))) float float4v;

DEV float bf2f(unsigned short u) { return __uint_as_float(((unsigned)u) << 16); }
DEV unsigned short f2bf_rtne(float f) {
    unsigned int b = __float_as_uint(f);
    b += 0x7FFFu + ((b >> 16) & 1u);
    return (unsigned short)(b >> 16);
}
DEV float actf(float x) { return x >= 0.f ? x : x * SLOPE; }
DEV void atomAddF(float* p, float v) {
#if defined(__HIP_DEVICE_COMPILE__)
    unsafeAtomicAdd(p, v);   // native global_atomic_add_f32; d_ws is coarse-grained
#endif
}
// dtype-adaptive load of float input i (isb=1: bf16 halves, isb=0: plain f32)
DEV float loadF(const void* p, size_t i, int isb) {
    return isb ? bf2f(((const unsigned short*)p)[i]) : ((const float*)p)[i];
}

// ============================ dtype sniff ============================
__global__ __launch_bounds__(64) void k_sniff(const unsigned short* __restrict__ pos, int* __restrict__ flag) {
    float v = bf2f(pos[threadIdx.x]);
    bool bad = !(fabsf(v) < 1e3f);          // catches huge, inf, NaN
    unsigned long long m = __ballot(bad);
    if (threadIdx.x == 0) flag[0] = (m == 0ull) ? 1 : 0;   // 1 = bf16, 0 = f32
}

__global__ __launch_bounds__(256) void k_fill16(unsigned short* __restrict__ out, int n, unsigned short val) {
    int i = blockIdx.x * 256 + threadIdx.x;
    if (i < n) out[i] = val;
}

// ============================ weight prep ============================
struct PrepArgs { const void* src[19]; void* dst[19]; };

__global__ __launch_bounds__(256) void k_prep(PrepArgs a, const int* __restrict__ flag) {
    // job type 3: bf16 MFMA B-fragment pack of W[3][64][192]:
    //   dst[((layer*6+c)*4+g)*64+l][8] <- B[k][n]=W[n][k], n=g*16+(l&15), k=c*32+(l>>4)*8+j
    // type 1: wave-sliced fp32 transpose dst[b][wv][k][hh] = W[b][wv*16+hh][k]
    // type 2: plain fp32 transpose dst[b][k][h] = W[b][h][k]  (K=128)
    // type 0: elementwise copy/convert to fp32
    constexpr int NJ = 19;
    constexpr int type[NJ] = {3,3,1,1,1,2, 0,0,0,0,0,0,0,0,0,0,0,0,0};
    constexpr int KD[NJ]   = {192,192,64,64,192,128, 0,0,0,0,0,0,0,0,0,0,0,0,0};
    constexpr int NEL[NJ]  = {36864,36864,12288,12288,12288,24576,
                              192,192,192,192,192,64,384,3,384,3,1024,64,64};
    const int isb = flag[0];
    int tid0 = blockIdx.x * blockDim.x + threadIdx.x;
    int stride = gridDim.x * blockDim.x;
    for (int j = 0; j < NJ; ++j) {
        const void* s = a.src[j];
        int n = NEL[j];
        if (type[j] == 0) {
            float* d = (float*)a.dst[j];
            for (int i = tid0; i < n; i += stride) d[i] = loadF(s, i, isb);
        } else if (type[j] == 1) {
            float* d = (float*)a.dst[j];
            int K = KD[j];
            for (int i = tid0; i < n; i += stride) {
                int hh = i & 15;
                int k  = (i >> 4) % K;
                int rest = i / (16 * K);      // b*4 + wv
                int wv = rest & 3, b = rest >> 2;
                d[i] = loadF(s, (size_t)(b*64 + wv*16 + hh) * K + k, isb);
            }
        } else if (type[j] == 2) {
            float* d = (float*)a.dst[j];
            int K = KD[j];
            for (int i = tid0; i < n; i += stride) {
                int h = i & 63;
                int k = (i >> 6) % K;
                int b = i / (64 * K);
                d[i] = loadF(s, (size_t)(b*64 + h) * K + k, isb);
            }
        } else {
            unsigned short* d = (unsigned short*)a.dst[j];
            for (int i = tid0; i < n; i += stride) {
                int layer = i / 12288;
                int r1 = i % 12288;
                int c  = r1 / 2048;
                int r2 = r1 % 2048;
                int g  = r2 / 512;
                int r3 = r2 % 512;
                int l  = r3 >> 3;
                int jj = r3 & 7;
                int nn = g * 16 + (l & 15);
                int k  = c * 32 + (l >> 4) * 8 + jj;
                d[i] = f2bf_rtne(loadF(s, (size_t)layer * 12288 + (size_t)nn * 192 + k, isb));
            }
        }
    }
}

// ============================ init kernels ============================
__global__ __launch_bounds__(256) void k_count_deg(const int* __restrict__ rowp, float* __restrict__ deg) {
    int e = blockIdx.x * 256 + threadIdx.x;
    if (e < Ee) atomAddF(&deg[rowp[e]], 1.0f);
}
__global__ __launch_bounds__(256) void k_deg_inv(float* __restrict__ deg) {
    int n = blockIdx.x * 256 + threadIdx.x;
    if (n < Nn) { float d = deg[n]; deg[n] = d > 0.f ? 1.0f / sqrtf(d) : 0.0f; }
}
__global__ __launch_bounds__(256) void k_node_init(const int* __restrict__ labels,
                                                   const float* __restrict__ posf,
                                                   float* __restrict__ node) {
    int idx = blockIdx.x * 256 + threadIdx.x;
    if (idx >= Nn * Hh) return;
    int n = idx >> 6, h = idx & 63;
    int pos = labels[2*n] * 4 + labels[2*n + 1];
    node[idx] = posf[pos * 64 + h];
}
__global__ __launch_bounds__(256) void k_set_rows(const int* __restrict__ positions,
                                                  const float* __restrict__ srcrow,
                                                  float* __restrict__ node) {
    int idx = blockIdx.x * 256 + threadIdx.x;
    if (idx >= BQ * Hh) return;
    int b = idx >> 6, h = idx & 63;
    node[(size_t)positions[b] * 64 + h] = srcrow[h];
}
__global__ __launch_bounds__(256) void k_rel_init(const int* __restrict__ qrel,
                                                  const float* __restrict__ srel,
                                                  float* __restrict__ rel) {
    int idx = blockIdx.x * 256 + threadIdx.x;
    if (idx >= BQ * Hh) return;
    int b = idx >> 6, h = idx & 63;
    rel[((size_t)qrel[b] + (size_t)b * Rr) * 64 + h] = srel[h];
}
__global__ __launch_bounds__(256) void k_loop_init(const float* __restrict__ l0, float* __restrict__ loop) {
    int idx = blockIdx.x * 256 + threadIdx.x;
    if (idx < BQ * Hh) loop[idx] = l0[idx & 63];
}

// ============================ alpha/beta pass ============================
__global__ __launch_bounds__(256) void k_ab(const float* __restrict__ rel,
                                            const int* __restrict__ et, const int* __restrict__ eqr,
                                            const int* __restrict__ rowp,
                                            const float* __restrict__ Wa, const float* __restrict__ ba,
                                            const float* __restrict__ Wb, const float* __restrict__ bb,
                                            float* __restrict__ a_vals, float* __restrict__ b_vals,
                                            float* __restrict__ a_sum, float* __restrict__ b_sum) {
    int tid = threadIdx.x, lane = tid & 63, wv = tid >> 6;
    int e = blockIdx.x * 4 + wv;
    int t = et[e], q = eqr[e];
    float r  = rel[(size_t)t * 64 + lane];
    float qv = rel[(size_t)q * 64 + lane];
    float pa = actf(r) * Wa[lane] + actf(qv) * Wa[64 + lane];
    float pb = r * Wb[lane] + qv * Wb[64 + lane];
    for (int off = 32; off; off >>= 1) { pa += __shfl_xor(pa, off); pb += __shfl_xor(pb, off); }
    if (lane == 0) {
        float av = expf(pa + ba[0]);
        float bv = expf(pb + bb[0]);
        a_vals[e] = av; b_vals[e] = bv;
        atomAddF(&a_sum[rowp[e]], av);
        atomAddF(&b_sum[t], bv);
    }
}

// ============================ MFMA edge message kernel ============================
// Block = 64 edges, 4 waves. feat (64 x 192) gathered fp32->bf16 into LDS
// (pitch 200 bf16 = 400 B; >=2-way max bank aliasing on frag reads = free).
// Weights pre-packed in B-fragment order, held in registers (12 frags/wave).
// Wave (wr,wc) computes edges [32wr,+32) x cols [32wc,+32) via
// mfma_f32_16x16x32_bf16; fp32 accumulate; fp32 epilogue + scatter atomics.
template<int KIND>   // 0 = msg1 (sources h/r/q, dst=node_new[row]), 1 = msg2 (h/t/q, dst=rel_new[et])
__global__ __launch_bounds__(256) void k_msg_mfma(
    const float* __restrict__ node, const float* __restrict__ rel,
    const int* __restrict__ col, const int* __restrict__ rowp,
    const int* __restrict__ et, const int* __restrict__ eqr,
    const unsigned short* __restrict__ Wfrag,   // [6][4][64][8] bf16 (this layer)
    const float* __restrict__ bias,             // [64] fp32
    const float* __restrict__ vals, const float* __restrict__ sums,
    const float* __restrict__ deg_inv,          // KIND==0 only
    float* __restrict__ dst)
{
    constexpr int P = 200;                       // bf16 pitch (400 B, 16B-aligned rows)
    __shared__ __align__(16) unsigned short feat[64 * P];
    __shared__ int s_src0[64], s_src1[64], s_src2[64], s_dst[64];
    __shared__ float s_coeff[64];
    const int tid = threadIdx.x;
    const int lane = tid & 63;
    const int wv = tid >> 6;
    const int e0 = blockIdx.x * 64;

    if (tid < 64) {
        int e = e0 + tid;
        int c = col[e], r = rowp[e], t = et[e], q = eqr[e];
        if (KIND == 0) {
            s_src0[tid] = c; s_src1[tid] = t; s_src2[tid] = q; s_dst[tid] = r;
            int rr = rowp[r];                               // faithful double index
            float dn = deg_inv[r] * deg_inv[c];
            s_coeff[tid] = vals[e] / (sums[rr] + 1e-10f) * dn * dn;   // ent_norm twice
        } else {
            s_src0[tid] = c; s_src1[tid] = r; s_src2[tid] = q; s_dst[tid] = t;
            int tt = et[t];                                 // faithful double index
            s_coeff[tid] = vals[e] / (sums[tt] + 1e-10f);
        }
    }

    // B fragments for this wave's 32 output cols (independent of LDS; overlaps idx load)
    const int wr = wv >> 1, wc = wv & 1;
    short8v bf[2][6];
#pragma unroll
    for (int tc = 0; tc < 2; ++tc) {
        int g = wc * 2 + tc;
#pragma unroll
        for (int c = 0; c < 6; ++c)
            bf[tc][c] = *(const short8v*)(Wfrag + (((size_t)c * 4 + g) * 64 + lane) * 8);
    }
    __syncthreads();

    // ---- stage: gather 192 rows (64 edges x 3 parts), fp32 -> bf16 ----
    {
        const int half = lane >> 5, ls = lane & 31;
#pragma unroll 4
        for (int t2 = 0; t2 < 24; ++t2) {
            int unit = wv * 48 + t2 * 2 + half;     // unit = part*64 + e
            int e = unit & 63, part = unit >> 6;
            int srow = part == 0 ? s_src0[e] : (part == 1 ? s_src1[e] : s_src2[e]);
            const float* base;
            if (KIND == 0) base = (part == 0) ? node : rel;
            else           base = (part == 2) ? rel : node;
            const float2 v = *(const float2*)(base + (size_t)srow * 64 + ls * 2);
            unsigned int u0 = __float_as_uint(v.x); u0 += 0x7FFFu + ((u0 >> 16) & 1u);
            unsigned int u1 = __float_as_uint(v.y); u1 += 0x7FFFu + ((u1 >> 16) & 1u);
            unsigned int pk = (u0 >> 16) | (u1 & 0xFFFF0000u);
            *(unsigned int*)(feat + e * P + part * 64 + ls * 2) = pk;
        }
    }
    __syncthreads();

    // ---- MFMA: 6 K-chunks x 4 tiles ----
    const int m = lane & 15, qd = lane >> 4;
    float4v zero = {0.f, 0.f, 0.f, 0.f};
    float4v acc[2][2];
    acc[0][0] = zero; acc[0][1] = zero; acc[1][0] = zero; acc[1][1] = zero;
#pragma unroll
    for (int c = 0; c < 6; ++c) {
        short8v a0 = *(const short8v*)(feat + (wr * 32 + m) * P + c * 32 + qd * 8);
        short8v a1 = *(const short8v*)(feat + (wr * 32 + 16 + m) * P + c * 32 + qd * 8);
        acc[0][0] = __builtin_amdgcn_mfma_f32_16x16x32_bf16(a0, bf[0][c], acc[0][0], 0, 0, 0);
        acc[0][1] = __builtin_amdgcn_mfma_f32_16x16x32_bf16(a0, bf[1][c], acc[0][1], 0, 0, 0);
        acc[1][0] = __builtin_amdgcn_mfma_f32_16x16x32_bf16(a1, bf[0][c], acc[1][0], 0, 0, 0);
        acc[1][1] = __builtin_amdgcn_mfma_f32_16x16x32_bf16(a1, bf[1][c], acc[1][1], 0, 0, 0);
    }

    // ---- epilogue: act+bias, coeff scale, scatter atomics ----
#pragma unroll
    for (int tc = 0; tc < 2; ++tc) {
        int h = wc * 32 + tc * 16 + m;              // C/D: col = lane&15
        float bi = bias[h];
#pragma unroll
        for (int tr = 0; tr < 2; ++tr) {
#pragma unroll
            for (int r = 0; r < 4; ++r) {           // C/D: row = (lane>>4)*4 + reg
                int er = wr * 32 + tr * 16 + qd * 4 + r;
                float v = actf(acc[tr][tc][r] + bi) * s_coeff[er];
                atomAddF(&dst[(size_t)s_dst[er] * 64 + h], v);
            }
        }
    }
}

// ============================ row-wise 64x64 transform + LN ============================
__global__ __launch_bounds__(256) void k_ent_ln(const float* __restrict__ x,    // node_new
                                                const float* __restrict__ Wv,   // [4][64][16]
                                                const float* __restrict__ bias,
                                                float* __restrict__ out) {      // node_emb
    __shared__ float xT[64 * 65];
    int tid = threadIdx.x, lane = tid & 63;
    int wv = tid >> 6;
    size_t n0 = (size_t)blockIdx.x * 64;
    for (int j = wv; j < 64; j += 4) xT[lane * 65 + j] = x[(n0 + j) * 64 + lane];
    __syncthreads();
    float acc[16];
#pragma unroll
    for (int h = 0; h < 16; ++h) acc[h] = 0.f;
    const float* Wl = Wv + wv * (64 * 16);
    for (int k = 0; k < 64; ++k) {
        float f = xT[k * 65 + lane];
        const float* wr = Wl + k * 16;
#pragma unroll
        for (int hh = 0; hh < 16; ++hh) acc[hh] = fmaf(f, wr[hh], acc[hh]);
    }
    __syncthreads();
    float* yT = xT;
#pragma unroll
    for (int hh = 0; hh < 16; ++hh) {
        int h = wv * 16 + hh;
        yT[h * 65 + lane] = actf(acc[hh] + bias[h]);
    }
    __syncthreads();
    for (int jj = 0; jj < 16; ++jj) {
        int j = wv * 16 + jj;
        float v = yT[lane * 65 + j];
        float s = v, s2 = v * v;
        for (int off = 32; off; off >>= 1) { s += __shfl_xor(s, off); s2 += __shfl_xor(s2, off); }
        float mean = s * (1.f / 64.f);
        float var = s2 * (1.f / 64.f) - mean * mean;
        if (var < 0.f) var = 0.f;
        out[(n0 + j) * 64 + lane] = (v - mean) / sqrtf(var + EPS_LN);
    }
}

__global__ __launch_bounds__(256) void k_rel_ln(const float* __restrict__ x,    // rel_new (agg)
                                                const float* __restrict__ Wv, const float* __restrict__ bias,
                                                float* __restrict__ rel,        // in-place update
                                                float* __restrict__ fin_i) {    // finals[i]
    __shared__ float xT[64 * 65];
    int tid = threadIdx.x, lane = tid & 63;
    int wv = tid >> 6;
    size_t r0 = (size_t)blockIdx.x * 64;
    for (int j = wv; j < 64; j += 4) xT[lane * 65 + j] = x[(r0 + j) * 64 + lane];
    __syncthreads();
    float acc[16];
#pragma unroll
    for (int h = 0; h < 16; ++h) acc[h] = 0.f;
    const float* Wl = Wv + wv * (64 * 16);
    for (int k = 0; k < 64; ++k) {
        float f = xT[k * 65 + lane];
        const float* wr = Wl + k * 16;
#pragma unroll
        for (int hh = 0; hh < 16; ++hh) acc[hh] = fmaf(f, wr[hh], acc[hh]);
    }
    __syncthreads();
    float* yT = xT;
#pragma unroll
    for (int hh = 0; hh < 16; ++hh) {
        int h = wv * 16 + hh;
        yT[h * 65 + lane] = actf(acc[hh] + bias[h]);
    }
    __syncthreads();
    for (int jj = 0; jj < 16; ++jj) {
        int j = wv * 16 + jj;
        float v = yT[lane * 65 + j] + rel[(r0 + j) * 64 + lane];   // residual
        float s = v, s2 = v * v;
        for (int off = 32; off; off >>= 1) { s += __shfl_xor(s, off); s2 += __shfl_xor(s2, off); }
        float mean = s * (1.f / 64.f);
        float var = s2 * (1.f / 64.f) - mean * mean;
        if (var < 0.f) var = 0.f;
        float nv = (v - mean) / sqrtf(var + EPS_LN);
        rel[(r0 + j) * 64 + lane] = nv;
        fin_i[(r0 + j) * 64 + lane] = nv;
    }
}

__global__ __launch_bounds__(64) void k_loop_upd(const float* __restrict__ rel, const int* __restrict__ qrel,
                                                 const float* __restrict__ Wt,   // [128][64] plain transposed
                                                 const float* __restrict__ bias,
                                                 float* __restrict__ loop) {
    __shared__ float cat[128];
    int b = blockIdx.x, lane = threadIdx.x;
    float lv = loop[b * 64 + lane];
    int qr = qrel[b] + b * Rr;
    cat[lane] = lv;
    cat[64 + lane] = rel[(size_t)qr * 64 + lane];
    __syncthreads();
    float acc = 0.f;
    for (int k = 0; k < 128; ++k) acc = fmaf(cat[k], Wt[k * 64 + lane], acc);
    float v = lv + actf(acc + bias[lane]);
    float s = v, s2 = v * v;
    for (int off = 32; off; off >>= 1) { s += __shfl_xor(s, off); s2 += __shfl_xor(s2, off); }
    float mean = s * (1.f / 64.f);
    float var = s2 * (1.f / 64.f) - mean * mean;
    if (var < 0.f) var = 0.f;
    loop[b * 64 + lane] = (v - mean) / sqrtf(var + EPS_LN);
}

// ============================ final projection + LN ============================
__global__ __launch_bounds__(256) void k_final(const float* __restrict__ finals,  // [3][Rt][64]
                                               const float* __restrict__ Wv,      // [4][192][16]
                                               const float* __restrict__ bias,
                                               float* __restrict__ fin_ln) {
    __shared__ float featT[192 * 65];
    int tid = threadIdx.x, lane = tid & 63;
    int wv = tid >> 6;
    size_t r0 = (size_t)blockIdx.x * 64;
    for (int j = wv; j < 192; j += 4) {
        int e = j / 3, part = j - e * 3;
        featT[(part * 64 + lane) * 65 + e] = finals[(size_t)part * Rt * 64 + (r0 + e) * 64 + lane];
    }
    __syncthreads();
    float acc[16];
#pragma unroll
    for (int h = 0; h < 16; ++h) acc[h] = 0.f;
    const float* Wl = Wv + wv * (192 * 16);
    for (int k = 0; k < 192; ++k) {
        float f = featT[k * 65 + lane];
        const float* wr = Wl + k * 16;
#pragma unroll
        for (int hh = 0; hh < 16; ++hh) acc[hh] = fmaf(f, wr[hh], acc[hh]);
    }
    __syncthreads();
    float* yT = featT;
#pragma unroll
    for (int hh = 0; hh < 16; ++hh) {
        int h = wv * 16 + hh;
        yT[h * 65 + lane] = actf(acc[hh] + bias[h]);
    }
    __syncthreads();
    for (int jj = 0; jj < 16; ++jj) {
        int j = wv * 16 + jj;
        float v = yT[lane * 65 + j];
        float s = v, s2 = v * v;
        for (int off = 32; off; off >>= 1) { s += __shfl_xor(s, off); s2 += __shfl_xor(s2, off); }
        float mean = s * (1.f / 64.f);
        float var = s2 * (1.f / 64.f) - mean * mean;
        if (var < 0.f) var = 0.f;
        fin_ln[(r0 + j) * 64 + lane] = (v - mean) / sqrtf(var + EPS_LN);
    }
}

__global__ __launch_bounds__(256) void k_out(const float* __restrict__ fin_ln,
                                             const float* __restrict__ loop,
                                             void* __restrict__ out, int n,
                                             const int* __restrict__ flag) {
    int idx = blockIdx.x * 256 + threadIdx.x;
    if (idx >= n) return;
    int h = idx & 63;
    int j = (idx >> 6) % (Rr + 1);
    int g = idx / ((Rr + 1) * 64);
    float v = 0.f;
    if (j < Rr) {
        for (int s = 0; s < SHOT; ++s)
            v += fin_ln[(size_t)((g * SHOT + s) * Rr + j) * 64 + h];
    } else {
        for (int s = 0; s < SHOT; ++s)
            v += loop[(g * SHOT + s) * 64 + h];
    }
    v *= (1.0f / SHOT);
    if (flag[0]) ((__hip_bfloat16*)out)[idx] = __float2bfloat16(v);
    else         ((float*)out)[idx] = v;
}

// ============================ host launch ============================
extern "C" void kernel_launch(void* const* d_in, const int* in_sizes, int n_in,
                              void* d_out, int out_size, void* d_ws, size_t ws_size,
                              hipStream_t stream) {
    // sentinel guards: absmax ~123 => ws too small; ~77 => wrong input count
    if (ws_size < off_end * 4 || n_in != 29) {
        k_fill16<<<(out_size + 255) / 256, 256, 0, stream>>>(
            (unsigned short*)d_out, out_size, (n_in != 29) ? (unsigned short)0x429A : (unsigned short)0x42F6);
        return;
    }

    const int* edge_index = (const int*)d_in[0];
    const int* col  = edge_index;          // edge_index[0] (h side)
    const int* rowp = edge_index + Ee;     // edge_index[1] (t side)
    const int* et   = (const int*)d_in[1];
    const int* eqr  = (const int*)d_in[2];
    const int* hpos = (const int*)d_in[3];
    const int* tpos = (const int*)d_in[4];
    const int* qrel = (const int*)d_in[5];
    const int* labels = (const int*)d_in[6];

    float* W = (float*)d_ws;
    int*   flag  = (int*)d_ws;             // ws[0]
    float* node  = W + off_node;
    float* node2 = W + off_node2;
    float* rel   = W + off_rel;
    float* rel2  = W + off_rel2;
    float* fin   = W + off_fin;
    float* finln = W + off_finln;
    float* loop  = W + off_loop;
    float* av    = W + off_av;
    float* bvv   = W + off_bvv;
    float* asum  = W + off_asum;
    float* bsum  = W + off_bsum;
    float* deg   = W + off_deg;
    unsigned short* WmsgF  = (unsigned short*)(W + off_WmsgF);
    unsigned short* Wht2rF = (unsigned short*)(W + off_Wht2rF);

    // --- dtype sniff then weight prep ---
    k_sniff<<<1, 64, 0, stream>>>((const unsigned short*)d_in[10], flag);
    PrepArgs pa;
    const int src_idx[19] = {13,15,23,25,27,21, 14,16,24,26,22,28,17,18,19,20,10,11,12};
    void* dsts[19] = {WmsgF, Wht2rF, W+off_Went, W+off_Wrel, W+off_Wfin, W+off_Wloop,
                      W+off_bmsg, W+off_bht2r, W+off_bent, W+off_brel, W+off_bloop, W+off_bfin,
                      W+off_Wa, W+off_ba, W+off_Wb, W+off_bb, W+off_pos, W+off_srel, W+off_loop0};
    for (int j = 0; j < 19; ++j) { pa.src[j] = d_in[src_idx[j]]; pa.dst[j] = dsts[j]; }
    k_prep<<<144, 256, 0, stream>>>(pa, flag);

    // --- degree / init ---
    (void)hipMemsetAsync(deg, 0, (size_t)Nn * 4, stream);
    k_count_deg<<<Ee / 256, 256, 0, stream>>>(rowp, deg);
    k_deg_inv<<<Nn / 256, 256, 0, stream>>>(deg);
    k_node_init<<<(Nn * Hh) / 256, 256, 0, stream>>>(labels, W + off_pos, node);
    k_set_rows<<<(BQ * Hh + 255) / 256, 256, 0, stream>>>(hpos, W + off_pos, node);        // pos_emb[0]
    k_set_rows<<<(BQ * Hh + 255) / 256, 256, 0, stream>>>(tpos, W + off_pos + 64, node);   // pos_emb[1]
    (void)hipMemsetAsync(rel, 0, (size_t)Rt * Hh * 4, stream);
    k_rel_init<<<(BQ * Hh + 255) / 256, 256, 0, stream>>>(qrel, W + off_srel, rel);
    k_loop_init<<<(BQ * Hh + 255) / 256, 256, 0, stream>>>(W + off_loop0, loop);

    // --- layers ---
    for (int i = 0; i < 3; ++i) {
        (void)hipMemsetAsync(asum, 0, (size_t)Nn * 4, stream);
        (void)hipMemsetAsync(bsum, 0, (size_t)Rt * 4, stream);
        k_ab<<<Ee / 4, 256, 0, stream>>>(rel, et, eqr, rowp,
                                         W + off_Wa + i * 128, W + off_ba + i,
                                         W + off_Wb + i * 128, W + off_bb + i,
                                         av, bvv, asum, bsum);
        (void)hipMemsetAsync(node2, 0, (size_t)Nn * Hh * 4, stream);
        k_msg_mfma<0><<<Ee / 64, 256, 0, stream>>>(node, rel, col, rowp, et, eqr,
                                                   WmsgF + (size_t)i * 12288, W + off_bmsg + i * 64,
                                                   av, asum, deg, node2);
        k_ent_ln<<<Nn / 64, 256, 0, stream>>>(node2, W + off_Went + (size_t)i * 4096,
                                              W + off_bent + i * 64, node);
        (void)hipMemsetAsync(rel2, 0, (size_t)Rt * Hh * 4, stream);
        k_msg_mfma<1><<<Ee / 64, 256, 0, stream>>>(node, rel, col, rowp, et, eqr,
                                                   Wht2rF + (size_t)i * 12288, W + off_bht2r + i * 64,
                                                   bvv, bsum, deg, rel2);
        k_rel_ln<<<Rt / 64, 256, 0, stream>>>(rel2, W + off_Wrel + (size_t)i * 4096,
                                              W + off_brel + i * 64, rel, fin + (size_t)i * Rt * Hh);
        k_loop_upd<<<BQ, 64, 0, stream>>>(rel, qrel, W + off_Wloop + (size_t)i * 8192,
                                          W + off_bloop + i * 64, loop);
    }

    // --- final projection, LN, shot-mean, output ---
    k_final<<<Rt / 64, 256, 0, stream>>>(fin, W + off_Wfin, W + off_bfin, finln);
    k_out<<<(out_size + 255) / 256, 256, 0, stream>>>(finln, loop, d_out, out_size, flag);
}

// Round 4
// 933.638 us; speedup vs baseline: 3.2849x; 1.1473x over previous
//
#include <hip/hip_runtime.h>
#include <hip/hip_bf16.h>

#define DEV __device__ __forceinline__

// ---------------- problem constants (fixed by setup_inputs) ----------------
constexpr int Nn   = 65536;        // num_ent
constexpr int Ee   = 262144;       // edges
constexpr int Rr   = 200;          // relation_num
constexpr int BQ   = 40;           // batch queries
constexpr int Rt   = Rr * BQ;      // 8000
constexpr int Hh   = 64;
constexpr int SHOT = 5;
constexpr float SLOPE  = 0.22916667f;   // (1/8 + 1/3)/2
constexpr float EPS_LN = 1e-5f;

// ---------------- workspace layout (float offsets); ws[0..15] = flag block ----
// node/rel tables are bf16 (u16), counted here in float units (/2).
constexpr size_t BASE = 16;
constexpr size_t off_node   = BASE;                              // bf16 Nn*64
constexpr size_t off_node2  = off_node  + (size_t)Nn*Hh/2;       // fp32 accum
constexpr size_t off_rel    = off_node2 + (size_t)Nn*Hh;         // bf16 Rt*64
constexpr size_t off_rel2   = off_rel   + (size_t)Rt*Hh/2;       // fp32 accum
constexpr size_t off_fin    = off_rel2  + (size_t)Rt*Hh;         // fp32, 3 slabs
constexpr size_t off_finln  = off_fin   + (size_t)3*Rt*Hh;
constexpr size_t off_loop   = off_finln + (size_t)Rt*Hh;
constexpr size_t off_av     = off_loop  + (size_t)BQ*Hh;
constexpr size_t off_bvv    = off_av    + (size_t)Ee;
constexpr size_t off_asum   = off_bvv   + (size_t)Ee;
constexpr size_t off_bsum   = off_asum  + (size_t)Nn;            // contiguous after asum
constexpr size_t off_deg    = off_bsum  + (size_t)Rt;
constexpr size_t off_uv     = off_deg   + (size_t)Nn;            // 4*Rt (ua,va,ub,vb)
constexpr size_t off_Went   = off_uv    + (size_t)4*Rt;
constexpr size_t off_Wrel   = off_Went  + (size_t)3*64*64;
constexpr size_t off_Wfin   = off_Wrel  + (size_t)3*64*64;
constexpr size_t off_Wloop  = off_Wfin  + (size_t)192*64;
constexpr size_t off_bmsg   = off_Wloop + (size_t)3*128*64;
constexpr size_t off_bht2r  = off_bmsg  + 192;
constexpr size_t off_bent   = off_bht2r + 192;
constexpr size_t off_brel   = off_bent  + 192;
constexpr size_t off_bloop  = off_brel  + 192;
constexpr size_t off_bfin   = off_bloop + 192;
constexpr size_t off_Wa     = off_bfin  + 64;
constexpr size_t off_ba     = off_Wa    + 384;
constexpr size_t off_Wb     = off_ba    + 4;
constexpr size_t off_bb     = off_Wb    + 384;
constexpr size_t off_pos    = off_bb    + 4;
constexpr size_t off_srel   = off_pos   + 1024;
constexpr size_t off_loop0  = off_srel  + 64;
// bf16 fragment-packed msg weights (each: 3 layers x 12288 u16 = 18432 floats)
constexpr size_t off_WmsgF  = off_loop0 + 64;
constexpr size_t off_Wht2rF = off_WmsgF + 18432;
constexpr size_t off_end    = off_Wht2rF + 18432;

typedef __attribute__((ext_vector_type(8))) short short8v;
typedef __attribute__((ext_vector_type(4))) float float4v;

DEV float bf2f(unsigned short u) { return __uint_as_float(((unsigned)u) << 16); }
DEV unsigned short f2bf_rtne(float f) {
    unsigned int b = __float_as_uint(f);
    b += 0x7FFFu + ((b >> 16) & 1u);
    return (unsigned short)(b >> 16);
}
DEV float actf(float x) { return x >= 0.f ? x : x * SLOPE; }
DEV void atomAddF(float* p, float v) {
#if defined(__HIP_DEVICE_COMPILE__)
    unsafeAtomicAdd(p, v);   // native global_atomic_add_f32; d_ws is coarse-grained
#endif
}
// dtype-adaptive load of float input i (isb=1: bf16 halves, isb=0: plain f32)
DEV float loadF(const void* p, size_t i, int isb) {
    return isb ? bf2f(((const unsigned short*)p)[i]) : ((const float*)p)[i];
}

// ============================ dtype sniff ============================
__global__ __launch_bounds__(64) void k_sniff(const unsigned short* __restrict__ pos, int* __restrict__ flag) {
    float v = bf2f(pos[threadIdx.x]);
    bool bad = !(fabsf(v) < 1e3f);          // catches huge, inf, NaN
    unsigned long long m = __ballot(bad);
    if (threadIdx.x == 0) flag[0] = (m == 0ull) ? 1 : 0;   // 1 = bf16, 0 = f32
}

__global__ __launch_bounds__(256) void k_fill16(unsigned short* __restrict__ out, int n, unsigned short val) {
    int i = blockIdx.x * 256 + threadIdx.x;
    if (i < n) out[i] = val;
}

// ============================ weight prep (+ deg/rel zero) ============================
struct PrepArgs { const void* src[19]; void* dst[19]; };

__global__ __launch_bounds__(256) void k_prep(PrepArgs a, const int* __restrict__ flag,
                                              float* __restrict__ deg, unsigned int* __restrict__ relz) {
    constexpr int NJ = 19;
    constexpr int type[NJ] = {3,3,1,1,1,2, 0,0,0,0,0,0,0,0,0,0,0,0,0};
    constexpr int KD[NJ]   = {192,192,64,64,192,128, 0,0,0,0,0,0,0,0,0,0,0,0,0};
    constexpr int NEL[NJ]  = {36864,36864,12288,12288,12288,24576,
                              192,192,192,192,192,64,384,3,384,3,1024,64,64};
    const int isb = flag[0];
    int tid0 = blockIdx.x * blockDim.x + threadIdx.x;
    int stride = gridDim.x * blockDim.x;
    for (int j = 0; j < NJ; ++j) {
        const void* s = a.src[j];
        int n = NEL[j];
        if (type[j] == 0) {
            float* d = (float*)a.dst[j];
            for (int i = tid0; i < n; i += stride) d[i] = loadF(s, i, isb);
        } else if (type[j] == 1) {
            float* d = (float*)a.dst[j];
            int K = KD[j];
            for (int i = tid0; i < n; i += stride) {
                int hh = i & 15;
                int k  = (i >> 4) % K;
                int rest = i / (16 * K);      // b*4 + wv
                int wv = rest & 3, b = rest >> 2;
                d[i] = loadF(s, (size_t)(b*64 + wv*16 + hh) * K + k, isb);
            }
        } else if (type[j] == 2) {
            float* d = (float*)a.dst[j];
            int K = KD[j];
            for (int i = tid0; i < n; i += stride) {
                int h = i & 63;
                int k = (i >> 6) % K;
                int b = i / (64 * K);
                d[i] = loadF(s, (size_t)(b*64 + h) * K + k, isb);
            }
        } else {
            unsigned short* d = (unsigned short*)a.dst[j];
            for (int i = tid0; i < n; i += stride) {
                int layer = i / 12288;
                int r1 = i % 12288;
                int c  = r1 / 2048;
                int r2 = r1 % 2048;
                int g  = r2 / 512;
                int r3 = r2 % 512;
                int l  = r3 >> 3;
                int jj = r3 & 7;
                int nn = g * 16 + (l & 15);
                int k  = c * 32 + (l >> 4) * 8 + jj;
                d[i] = f2bf_rtne(loadF(s, (size_t)layer * 12288 + (size_t)nn * 192 + k, isb));
            }
        }
    }
    // zero deg (Nn fp32) and rel table (Rt*64 bf16 = Rt*32 uint)
    for (int i = tid0; i < Nn; i += stride) deg[i] = 0.f;
    for (int i = tid0; i < Rt * 32; i += stride) relz[i] = 0u;
}

// ============================ init kernels ============================
__global__ __launch_bounds__(256) void k_count_deg(const int* __restrict__ rowp, float* __restrict__ deg) {
    int e = blockIdx.x * 256 + threadIdx.x;
    if (e < Ee) atomAddF(&deg[rowp[e]], 1.0f);
}
__global__ __launch_bounds__(256) void k_deg_inv(float* __restrict__ deg) {
    int n = blockIdx.x * 256 + threadIdx.x;
    if (n < Nn) { float d = deg[n]; deg[n] = d > 0.f ? 1.0f / sqrtf(d) : 0.0f; }
}
__global__ __launch_bounds__(256) void k_node_init(const int* __restrict__ labels,
                                                   const float* __restrict__ posf,
                                                   unsigned short* __restrict__ node) {
    int idx = blockIdx.x * 256 + threadIdx.x;
    if (idx >= Nn * Hh) return;
    int n = idx >> 6, h = idx & 63;
    int pos = labels[2*n] * 4 + labels[2*n + 1];
    node[idx] = f2bf_rtne(posf[pos * 64 + h]);
}
__global__ __launch_bounds__(256) void k_set_rows(const int* __restrict__ positions,
                                                  const float* __restrict__ srcrow,
                                                  unsigned short* __restrict__ node) {
    int idx = blockIdx.x * 256 + threadIdx.x;
    if (idx >= BQ * Hh) return;
    int b = idx >> 6, h = idx & 63;
    node[(size_t)positions[b] * 64 + h] = f2bf_rtne(srcrow[h]);
}
__global__ __launch_bounds__(256) void k_rel_init(const int* __restrict__ qrel,
                                                  const float* __restrict__ srel,
                                                  unsigned short* __restrict__ rel) {
    int idx = blockIdx.x * 256 + threadIdx.x;
    if (idx >= BQ * Hh) return;
    int b = idx >> 6, h = idx & 63;
    rel[((size_t)qrel[b] + (size_t)b * Rr) * 64 + h] = f2bf_rtne(srel[h]);
}
__global__ __launch_bounds__(256) void k_loop_init(const float* __restrict__ l0, float* __restrict__ loop) {
    int idx = blockIdx.x * 256 + threadIdx.x;
    if (idx < BQ * Hh) loop[idx] = l0[idx & 63];
}

// ============================ per-relation alpha/beta factors + zeroing ============================
// a_e = exp(ua[et]+va[eqr]+ba) since W_alpha splits over the concat halves.
// Also zeroes asum/bsum/node2/rel2 for this layer (grid-stride).
__global__ __launch_bounds__(256) void k_uv(const unsigned short* __restrict__ rel,
                                            const float* __restrict__ Wa, const float* __restrict__ Wb,
                                            float* __restrict__ uv,
                                            float* __restrict__ asum,      // asum+bsum contiguous
                                            float4v* __restrict__ node2, float4v* __restrict__ rel2) {
    int tid = threadIdx.x, lane = tid & 63, wv = tid >> 6;
    int w = blockIdx.x * 4 + wv;
    if (w < Rt) {
        float x = bf2f(rel[(size_t)w * 64 + lane]);
        float ax = actf(x);
        float pua = ax * Wa[lane], pva = ax * Wa[64 + lane];
        float pub = x * Wb[lane],  pvb = x * Wb[64 + lane];
        for (int off = 32; off; off >>= 1) {
            pua += __shfl_xor(pua, off); pva += __shfl_xor(pva, off);
            pub += __shfl_xor(pub, off); pvb += __shfl_xor(pvb, off);
        }
        if (lane == 0) {
            uv[w] = pua; uv[Rt + w] = pva; uv[2 * Rt + w] = pub; uv[3 * Rt + w] = pvb;
        }
    }
    // grid-stride zeroing
    int tid0 = blockIdx.x * 256 + tid;
    int stride = gridDim.x * 256;
    float4v z = {0.f, 0.f, 0.f, 0.f};
    for (int i = tid0; i < Nn + Rt; i += stride) asum[i] = 0.f;
    for (int i = tid0; i < Nn * 16; i += stride) node2[i] = z;
    for (int i = tid0; i < Rt * 16; i += stride) rel2[i] = z;
}

__global__ __launch_bounds__(256) void k_ab_edge(const int* __restrict__ et, const int* __restrict__ eqr,
                                                 const int* __restrict__ rowp,
                                                 const float* __restrict__ uv,
                                                 const float* __restrict__ ba, const float* __restrict__ bb,
                                                 float* __restrict__ a_vals, float* __restrict__ b_vals,
                                                 float* __restrict__ a_sum, float* __restrict__ b_sum) {
    int e = blockIdx.x * 256 + threadIdx.x;
    if (e >= Ee) return;
    int t = et[e], q = eqr[e];
    float av = expf(uv[t] + uv[Rt + q] + ba[0]);
    float bv = expf(uv[2 * Rt + t] + uv[3 * Rt + q] + bb[0]);
    a_vals[e] = av; b_vals[e] = bv;
    atomAddF(&a_sum[rowp[e]], av);
    atomAddF(&b_sum[t], bv);
}

// ============================ MFMA edge message kernel ============================
// Block = 64 edges, 4 waves. feat (64 x 192 bf16) gathered into LDS (pitch 200).
// Tables are bf16 -> gather is straight uint copies (no convert VALU).
template<int KIND>   // 0 = msg1 (h/r/q, dst=node_new[row]), 1 = msg2 (h/t/q, dst=rel_new[et])
__global__ __launch_bounds__(256) void k_msg_mfma(
    const unsigned short* __restrict__ node, const unsigned short* __restrict__ rel,
    const int* __restrict__ col, const int* __restrict__ rowp,
    const int* __restrict__ et, const int* __restrict__ eqr,
    const unsigned short* __restrict__ Wfrag,   // [6][4][64][8] bf16 (this layer)
    const float* __restrict__ bias,             // [64] fp32
    const float* __restrict__ vals, const float* __restrict__ sums,
    const float* __restrict__ deg_inv,          // KIND==0 only
    float* __restrict__ dst)
{
    constexpr int P = 200;                       // bf16 pitch (400 B rows)
    __shared__ __align__(16) unsigned short feat[64 * P];
    __shared__ int s_src0[64], s_src1[64], s_src2[64], s_dst[64];
    __shared__ float s_coeff[64];
    const int tid = threadIdx.x;
    const int lane = tid & 63;
    const int wv = tid >> 6;
    const int e0 = blockIdx.x * 64;

    if (tid < 64) {
        int e = e0 + tid;
        int c = col[e], r = rowp[e], t = et[e], q = eqr[e];
        if (KIND == 0) {
            s_src0[tid] = c; s_src1[tid] = t; s_src2[tid] = q; s_dst[tid] = r;
            int rr = rowp[r];                               // faithful double index
            float dn = deg_inv[r] * deg_inv[c];
            s_coeff[tid] = vals[e] / (sums[rr] + 1e-10f) * dn * dn;   // ent_norm twice
        } else {
            s_src0[tid] = c; s_src1[tid] = r; s_src2[tid] = q; s_dst[tid] = t;
            int tt = et[t];                                 // faithful double index
            s_coeff[tid] = vals[e] / (sums[tt] + 1e-10f);
        }
    }

    // B fragments for this wave's 32 output cols
    const int wr = wv >> 1, wc = wv & 1;
    short8v bf[2][6];
#pragma unroll
    for (int tc = 0; tc < 2; ++tc) {
        int g = wc * 2 + tc;
#pragma unroll
        for (int c = 0; c < 6; ++c)
            bf[tc][c] = *(const short8v*)(Wfrag + (((size_t)c * 4 + g) * 64 + lane) * 8);
    }
    __syncthreads();

    // ---- stage: gather 192 bf16 rows (64 edges x 3 parts), 128 B each ----
    {
        const int half = lane >> 5, ls = lane & 31;
#pragma unroll 4
        for (int t2 = 0; t2 < 24; ++t2) {
            int unit = wv * 48 + t2 * 2 + half;     // unit = part*64 + e
            int e = unit & 63, part = unit >> 6;
            int srow = part == 0 ? s_src0[e] : (part == 1 ? s_src1[e] : s_src2[e]);
            const unsigned short* base;
            if (KIND == 0) base = (part == 0) ? node : rel;
            else           base = (part == 2) ? rel : node;
            ((unsigned int*)(feat + (size_t)e * P + part * 64))[ls] =
                ((const unsigned int*)(base + (size_t)srow * 64))[ls];
        }
    }
    __syncthreads();

    // ---- MFMA: 6 K-chunks x 4 tiles ----
    const int m = lane & 15, qd = lane >> 4;
    float4v zero = {0.f, 0.f, 0.f, 0.f};
    float4v acc[2][2];
    acc[0][0] = zero; acc[0][1] = zero; acc[1][0] = zero; acc[1][1] = zero;
#pragma unroll
    for (int c = 0; c < 6; ++c) {
        short8v a0 = *(const short8v*)(feat + (wr * 32 + m) * P + c * 32 + qd * 8);
        short8v a1 = *(const short8v*)(feat + (wr * 32 + 16 + m) * P + c * 32 + qd * 8);
        acc[0][0] = __builtin_amdgcn_mfma_f32_16x16x32_bf16(a0, bf[0][c], acc[0][0], 0, 0, 0);
        acc[0][1] = __builtin_amdgcn_mfma_f32_16x16x32_bf16(a0, bf[1][c], acc[0][1], 0, 0, 0);
        acc[1][0] = __builtin_amdgcn_mfma_f32_16x16x32_bf16(a1, bf[0][c], acc[1][0], 0, 0, 0);
        acc[1][1] = __builtin_amdgcn_mfma_f32_16x16x32_bf16(a1, bf[1][c], acc[1][1], 0, 0, 0);
    }

    // ---- epilogue: act+bias, coeff scale, scatter atomics ----
#pragma unroll
    for (int tc = 0; tc < 2; ++tc) {
        int h = wc * 32 + tc * 16 + m;              // C/D: col = lane&15
        float bi = bias[h];
#pragma unroll
        for (int tr = 0; tr < 2; ++tr) {
#pragma unroll
            for (int r = 0; r < 4; ++r) {           // C/D: row = (lane>>4)*4 + reg
                int er = wr * 32 + tr * 16 + qd * 4 + r;
                float v = actf(acc[tr][tc][r] + bi) * s_coeff[er];
                atomAddF(&dst[(size_t)s_dst[er] * 64 + h], v);
            }
        }
    }
}

// ============================ row-wise 64x64 transform + LN ============================
__global__ __launch_bounds__(256) void k_ent_ln(const float* __restrict__ x,    // node_new fp32
                                                const float* __restrict__ Wv,   // [4][64][16]
                                                const float* __restrict__ bias,
                                                unsigned short* __restrict__ out) { // node_emb bf16
    __shared__ float xT[64 * 65];
    int tid = threadIdx.x, lane = tid & 63;
    int wv = tid >> 6;
    size_t n0 = (size_t)blockIdx.x * 64;
    for (int j = wv; j < 64; j += 4) xT[lane * 65 + j] = x[(n0 + j) * 64 + lane];
    __syncthreads();
    float acc[16];
#pragma unroll
    for (int h = 0; h < 16; ++h) acc[h] = 0.f;
    const float* Wl = Wv + wv * (64 * 16);
    for (int k = 0; k < 64; ++k) {
        float f = xT[k * 65 + lane];
        const float* wr = Wl + k * 16;
#pragma unroll
        for (int hh = 0; hh < 16; ++hh) acc[hh] = fmaf(f, wr[hh], acc[hh]);
    }
    __syncthreads();
    float* yT = xT;
#pragma unroll
    for (int hh = 0; hh < 16; ++hh) {
        int h = wv * 16 + hh;
        yT[h * 65 + lane] = actf(acc[hh] + bias[h]);
    }
    __syncthreads();
    for (int jj = 0; jj < 16; ++jj) {
        int j = wv * 16 + jj;
        float v = yT[lane * 65 + j];
        float s = v, s2 = v * v;
        for (int off = 32; off; off >>= 1) { s += __shfl_xor(s, off); s2 += __shfl_xor(s2, off); }
        float mean = s * (1.f / 64.f);
        float var = s2 * (1.f / 64.f) - mean * mean;
        if (var < 0.f) var = 0.f;
        out[(n0 + j) * 64 + lane] = f2bf_rtne((v - mean) / sqrtf(var + EPS_LN));
    }
}

__global__ __launch_bounds__(256) void k_rel_ln(const float* __restrict__ x,    // rel_new (agg) fp32
                                                const float* __restrict__ Wv, const float* __restrict__ bias,
                                                unsigned short* __restrict__ rel,  // bf16, in-place update
                                                float* __restrict__ fin_i) {       // finals[i] fp32
    __shared__ float xT[64 * 65];
    int tid = threadIdx.x, lane = tid & 63;
    int wv = tid >> 6;
    size_t r0 = (size_t)blockIdx.x * 64;
    for (int j = wv; j < 64; j += 4) xT[lane * 65 + j] = x[(r0 + j) * 64 + lane];
    __syncthreads();
    float acc[16];
#pragma unroll
    for (int h = 0; h < 16; ++h) acc[h] = 0.f;
    const float* Wl = Wv + wv * (64 * 16);
    for (int k = 0; k < 64; ++k) {
        float f = xT[k * 65 + lane];
        const float* wr = Wl + k * 16;
#pragma unroll
        for (int hh = 0; hh < 16; ++hh) acc[hh] = fmaf(f, wr[hh], acc[hh]);
    }
    __syncthreads();
    float* yT = xT;
#pragma unroll
    for (int hh = 0; hh < 16; ++hh) {
        int h = wv * 16 + hh;
        yT[h * 65 + lane] = actf(acc[hh] + bias[h]);
    }
    __syncthreads();
    for (int jj = 0; jj < 16; ++jj) {
        int j = wv * 16 + jj;
        float v = yT[lane * 65 + j] + bf2f(rel[(r0 + j) * 64 + lane]);   // residual
        float s = v, s2 = v * v;
        for (int off = 32; off; off >>= 1) { s += __shfl_xor(s, off); s2 += __shfl_xor(s2, off); }
        float mean = s * (1.f / 64.f);
        float var = s2 * (1.f / 64.f) - mean * mean;
        if (var < 0.f) var = 0.f;
        float nv = (v - mean) / sqrtf(var + EPS_LN);
        rel[(r0 + j) * 64 + lane] = f2bf_rtne(nv);
        fin_i[(r0 + j) * 64 + lane] = nv;
    }
}

__global__ __launch_bounds__(64) void k_loop_upd(const unsigned short* __restrict__ rel,
                                                 const int* __restrict__ qrel,
                                                 const float* __restrict__ Wt,   // [128][64] plain transposed
                                                 const float* __restrict__ bias,
                                                 float* __restrict__ loop) {
    __shared__ float cat[128];
    int b = blockIdx.x, lane = threadIdx.x;
    float lv = loop[b * 64 + lane];
    int qr = qrel[b] + b * Rr;
    cat[lane] = lv;
    cat[64 + lane] = bf2f(rel[(size_t)qr * 64 + lane]);
    __syncthreads();
    float acc = 0.f;
    for (int k = 0; k < 128; ++k) acc = fmaf(cat[k], Wt[k * 64 + lane], acc);
    float v = lv + actf(acc + bias[lane]);
    float s = v, s2 = v * v;
    for (int off = 32; off; off >>= 1) { s += __shfl_xor(s, off); s2 += __shfl_xor(s2, off); }
    float mean = s * (1.f / 64.f);
    float var = s2 * (1.f / 64.f) - mean * mean;
    if (var < 0.f) var = 0.f;
    loop[b * 64 + lane] = (v - mean) / sqrtf(var + EPS_LN);
}

// ============================ final projection + LN ============================
__global__ __launch_bounds__(256) void k_final(const float* __restrict__ finals,  // [3][Rt][64]
                                               const float* __restrict__ Wv,      // [4][192][16]
                                               const float* __restrict__ bias,
                                               float* __restrict__ fin_ln) {
    __shared__ float featT[192 * 65];
    int tid = threadIdx.x, lane = tid & 63;
    int wv = tid >> 6;
    size_t r0 = (size_t)blockIdx.x * 64;
    for (int j = wv; j < 192; j += 4) {
        int e = j / 3, part = j - e * 3;
        featT[(part * 64 + lane) * 65 + e] = finals[(size_t)part * Rt * 64 + (r0 + e) * 64 + lane];
    }
    __syncthreads();
    float acc[16];
#pragma unroll
    for (int h = 0; h < 16; ++h) acc[h] = 0.f;
    const float* Wl = Wv + wv * (192 * 16);
    for (int k = 0; k < 192; ++k) {
        float f = featT[k * 65 + lane];
        const float* wr = Wl + k * 16;
#pragma unroll
        for (int hh = 0; hh < 16; ++hh) acc[hh] = fmaf(f, wr[hh], acc[hh]);
    }
    __syncthreads();
    float* yT = featT;
#pragma unroll
    for (int hh = 0; hh < 16; ++hh) {
        int h = wv * 16 + hh;
        yT[h * 65 + lane] = actf(acc[hh] + bias[h]);
    }
    __syncthreads();
    for (int jj = 0; jj < 16; ++jj) {
        int j = wv * 16 + jj;
        float v = yT[lane * 65 + j];
        float s = v, s2 = v * v;
        for (int off = 32; off; off >>= 1) { s += __shfl_xor(s, off); s2 += __shfl_xor(s2, off); }
        float mean = s * (1.f / 64.f);
        float var = s2 * (1.f / 64.f) - mean * mean;
        if (var < 0.f) var = 0.f;
        fin_ln[(r0 + j) * 64 + lane] = (v - mean) / sqrtf(var + EPS_LN);
    }
}

__global__ __launch_bounds__(256) void k_out(const float* __restrict__ fin_ln,
                                             const float* __restrict__ loop,
                                             void* __restrict__ out, int n,
                                             const int* __restrict__ flag) {
    int idx = blockIdx.x * 256 + threadIdx.x;
    if (idx >= n) return;
    int h = idx & 63;
    int j = (idx >> 6) % (Rr + 1);
    int g = idx / ((Rr + 1) * 64);
    float v = 0.f;
    if (j < Rr) {
        for (int s = 0; s < SHOT; ++s)
            v += fin_ln[(size_t)((g * SHOT + s) * Rr + j) * 64 + h];
    } else {
        for (int s = 0; s < SHOT; ++s)
            v += loop[(g * SHOT + s) * 64 + h];
    }
    v *= (1.0f / SHOT);
    if (flag[0]) ((__hip_bfloat16*)out)[idx] = __float2bfloat16(v);
    else         ((float*)out)[idx] = v;
}

// ============================ host launch ============================
extern "C" void kernel_launch(void* const* d_in, const int* in_sizes, int n_in,
                              void* d_out, int out_size, void* d_ws, size_t ws_size,
                              hipStream_t stream) {
    // sentinel guards: absmax ~123 => ws too small; ~77 => wrong input count
    if (ws_size < off_end * 4 || n_in != 29) {
        k_fill16<<<(out_size + 255) / 256, 256, 0, stream>>>(
            (unsigned short*)d_out, out_size, (n_in != 29) ? (unsigned short)0x429A : (unsigned short)0x42F6);
        return;
    }

    const int* edge_index = (const int*)d_in[0];
    const int* col  = edge_index;          // edge_index[0] (h side)
    const int* rowp = edge_index + Ee;     // edge_index[1] (t side)
    const int* et   = (const int*)d_in[1];
    const int* eqr  = (const int*)d_in[2];
    const int* hpos = (const int*)d_in[3];
    const int* tpos = (const int*)d_in[4];
    const int* qrel = (const int*)d_in[5];
    const int* labels = (const int*)d_in[6];

    float* W = (float*)d_ws;
    int*   flag  = (int*)d_ws;             // ws[0]
    unsigned short* node = (unsigned short*)(W + off_node);
    float* node2 = W + off_node2;
    unsigned short* rel = (unsigned short*)(W + off_rel);
    float* rel2  = W + off_rel2;
    float* fin   = W + off_fin;
    float* finln = W + off_finln;
    float* loop  = W + off_loop;
    float* av    = W + off_av;
    float* bvv   = W + off_bvv;
    float* asum  = W + off_asum;
    float* bsum  = W + off_bsum;
    float* deg   = W + off_deg;
    float* uv    = W + off_uv;
    unsigned short* WmsgF  = (unsigned short*)(W + off_WmsgF);
    unsigned short* Wht2rF = (unsigned short*)(W + off_Wht2rF);

    // --- dtype sniff then weight prep (prep also zeroes deg + rel table) ---
    k_sniff<<<1, 64, 0, stream>>>((const unsigned short*)d_in[10], flag);
    PrepArgs pa;
    const int src_idx[19] = {13,15,23,25,27,21, 14,16,24,26,22,28,17,18,19,20,10,11,12};
    void* dsts[19] = {WmsgF, Wht2rF, W+off_Went, W+off_Wrel, W+off_Wfin, W+off_Wloop,
                      W+off_bmsg, W+off_bht2r, W+off_bent, W+off_brel, W+off_bloop, W+off_bfin,
                      W+off_Wa, W+off_ba, W+off_Wb, W+off_bb, W+off_pos, W+off_srel, W+off_loop0};
    for (int j = 0; j < 19; ++j) { pa.src[j] = d_in[src_idx[j]]; pa.dst[j] = dsts[j]; }
    k_prep<<<144, 256, 0, stream>>>(pa, flag, deg, (unsigned int*)rel);

    // --- degree / init ---
    k_count_deg<<<Ee / 256, 256, 0, stream>>>(rowp, deg);
    k_deg_inv<<<Nn / 256, 256, 0, stream>>>(deg);
    k_node_init<<<(Nn * Hh) / 256, 256, 0, stream>>>(labels, W + off_pos, node);
    k_set_rows<<<(BQ * Hh + 255) / 256, 256, 0, stream>>>(hpos, W + off_pos, node);        // pos_emb[0]
    k_set_rows<<<(BQ * Hh + 255) / 256, 256, 0, stream>>>(tpos, W + off_pos + 64, node);   // pos_emb[1]
    k_rel_init<<<(BQ * Hh + 255) / 256, 256, 0, stream>>>(qrel, W + off_srel, rel);
    k_loop_init<<<(BQ * Hh + 255) / 256, 256, 0, stream>>>(W + off_loop0, loop);

    // --- layers ---
    for (int i = 0; i < 3; ++i) {
        k_uv<<<2048, 256, 0, stream>>>(rel, W + off_Wa + i * 128, W + off_Wb + i * 128,
                                       uv, asum, (float4v*)node2, (float4v*)rel2);
        k_ab_edge<<<Ee / 256, 256, 0, stream>>>(et, eqr, rowp, uv,
                                                W + off_ba + i, W + off_bb + i,
                                                av, bvv, asum, bsum);
        k_msg_mfma<0><<<Ee / 64, 256, 0, stream>>>(node, rel, col, rowp, et, eqr,
                                                   WmsgF + (size_t)i * 12288, W + off_bmsg + i * 64,
                                                   av, asum, deg, node2);
        k_ent_ln<<<Nn / 64, 256, 0, stream>>>(node2, W + off_Went + (size_t)i * 4096,
                                              W + off_bent + i * 64, node);
        k_msg_mfma<1><<<Ee / 64, 256, 0, stream>>>(node, rel, col, rowp, et, eqr,
                                                   Wht2rF + (size_t)i * 12288, W + off_bht2r + i * 64,
                                                   bvv, bsum, deg, rel2);
        k_rel_ln<<<Rt / 64, 256, 0, stream>>>(rel2, W + off_Wrel + (size_t)i * 4096,
                                              W + off_brel + i * 64, rel, fin + (size_t)i * Rt * Hh);
        k_loop_upd<<<BQ, 64, 0, stream>>>(rel, qrel, W + off_Wloop + (size_t)i * 8192,
                                          W + off_bloop + i * 64, loop);
    }

    // --- final projection, LN, shot-mean, output ---
    k_final<<<Rt / 64, 256, 0, stream>>>(fin, W + off_Wfin, W + off_bfin, finln);
    k_out<<<(out_size + 255) / 256, 256, 0, stream>>>(finln, loop, d_out, out_size, flag);
}

// Round 5
// 909.693 us; speedup vs baseline: 3.3713x; 1.0263x over previous
//
#include <hip/hip_runtime.h>
#include <hip/hip_bf16.h>

#define DEV __device__ __forceinline__

// ---------------- problem constants (fixed by setup_inputs) ----------------
constexpr int Nn   = 65536;        // num_ent
constexpr int Ee   = 262144;       // edges
constexpr int Rr   = 200;          // relation_num
constexpr int BQ   = 40;           // batch queries
constexpr int Rt   = Rr * BQ;      // 8000
constexpr int Hh   = 64;
constexpr int SHOT = 5;
constexpr float SLOPE  = 0.22916667f;   // (1/8 + 1/3)/2
constexpr float EPS_LN = 1e-5f;

// ---------------- workspace layout (float offsets); ws[0..15] = flag block ----
// node/rel tables bf16; node2/rel2 accumulators bf16 (slabs sized fp32 = slack).
constexpr size_t BASE = 16;
constexpr size_t off_node   = BASE;                              // bf16 Nn*64
constexpr size_t off_node2  = off_node  + (size_t)Nn*Hh/2;       // bf16 accum (fp32-sized slab)
constexpr size_t off_rel    = off_node2 + (size_t)Nn*Hh;         // bf16 Rt*64
constexpr size_t off_rel2   = off_rel   + (size_t)Rt*Hh/2;       // bf16 accum (fp32-sized slab)
constexpr size_t off_fin    = off_rel2  + (size_t)Rt*Hh;         // fp32, 3 slabs
constexpr size_t off_finln  = off_fin   + (size_t)3*Rt*Hh;
constexpr size_t off_loop   = off_finln + (size_t)Rt*Hh;
constexpr size_t off_av     = off_loop  + (size_t)BQ*Hh;
constexpr size_t off_bvv    = off_av    + (size_t)Ee;
constexpr size_t off_asum   = off_bvv   + (size_t)Ee;
constexpr size_t off_bsum   = off_asum  + (size_t)Nn;            // contiguous after asum
constexpr size_t off_deg    = off_bsum  + (size_t)Rt;
constexpr size_t off_uv     = off_deg   + (size_t)Nn;            // 4*Rt (ua,va,ub,vb)
constexpr size_t off_Went   = off_uv    + (size_t)4*Rt;
constexpr size_t off_Wrel   = off_Went  + (size_t)3*64*64;
constexpr size_t off_Wfin   = off_Wrel  + (size_t)3*64*64;
constexpr size_t off_Wloop  = off_Wfin  + (size_t)192*64;
constexpr size_t off_bmsg   = off_Wloop + (size_t)3*128*64;
constexpr size_t off_bht2r  = off_bmsg  + 192;
constexpr size_t off_bent   = off_bht2r + 192;
constexpr size_t off_brel   = off_bent  + 192;
constexpr size_t off_bloop  = off_brel  + 192;
constexpr size_t off_bfin   = off_bloop + 192;
constexpr size_t off_Wa     = off_bfin  + 64;
constexpr size_t off_ba     = off_Wa    + 384;
constexpr size_t off_Wb     = off_ba    + 4;
constexpr size_t off_bb     = off_Wb    + 384;
constexpr size_t off_pos    = off_bb    + 4;
constexpr size_t off_srel   = off_pos   + 1024;
constexpr size_t off_loop0  = off_srel  + 64;
// bf16 fragment-packed msg weights (each: 3 layers x 12288 u16 = 18432 floats)
constexpr size_t off_WmsgF  = off_loop0 + 64;
constexpr size_t off_Wht2rF = off_WmsgF + 18432;
constexpr size_t off_end    = off_Wht2rF + 18432;

typedef __attribute__((ext_vector_type(8))) short short8v;
typedef __attribute__((ext_vector_type(4))) float float4v;

DEV float bf2f(unsigned short u) { return __uint_as_float(((unsigned)u) << 16); }
DEV unsigned short f2bf_rtne(float f) {
    unsigned int b = __float_as_uint(f);
    b += 0x7FFFu + ((b >> 16) & 1u);
    return (unsigned short)(b >> 16);
}
DEV float actf(float x) { return x >= 0.f ? x : x * SLOPE; }
DEV void atomAddF(float* p, float v) {
#if defined(__HIP_DEVICE_COMPILE__)
    unsafeAtomicAdd(p, v);   // native global_atomic_add_f32; d_ws is coarse-grained
#endif
}
// packed bf16 atomic add: mem[p] += pk.lo ; mem[p+1] += pk.hi (bf16 RNE each)
DEV void atomPkAddBf16(unsigned short* p, unsigned int pk) {
#if defined(__HIP_DEVICE_COMPILE__)
    asm volatile("global_atomic_pk_add_bf16 %0, %1, off"
                 :: "v"((unsigned long long)p), "v"(pk) : "memory");
#endif
}
// dtype-adaptive load of float input i (isb=1: bf16 halves, isb=0: plain f32)
DEV float loadF(const void* p, size_t i, int isb) {
    return isb ? bf2f(((const unsigned short*)p)[i]) : ((const float*)p)[i];
}

// ============================ dtype sniff ============================
__global__ __launch_bounds__(64) void k_sniff(const unsigned short* __restrict__ pos, int* __restrict__ flag) {
    float v = bf2f(pos[threadIdx.x]);
    bool bad = !(fabsf(v) < 1e3f);          // catches huge, inf, NaN
    unsigned long long m = __ballot(bad);
    if (threadIdx.x == 0) flag[0] = (m == 0ull) ? 1 : 0;   // 1 = bf16, 0 = f32
}

__global__ __launch_bounds__(256) void k_fill16(unsigned short* __restrict__ out, int n, unsigned short val) {
    int i = blockIdx.x * 256 + threadIdx.x;
    if (i < n) out[i] = val;
}

// ============================ weight prep (+ deg/rel zero) ============================
struct PrepArgs { const void* src[19]; void* dst[19]; };

__global__ __launch_bounds__(256) void k_prep(PrepArgs a, const int* __restrict__ flag,
                                              int* __restrict__ degi, unsigned int* __restrict__ relz) {
    constexpr int NJ = 19;
    constexpr int type[NJ] = {3,3,1,1,1,2, 0,0,0,0,0,0,0,0,0,0,0,0,0};
    constexpr int KD[NJ]   = {192,192,64,64,192,128, 0,0,0,0,0,0,0,0,0,0,0,0,0};
    constexpr int NEL[NJ]  = {36864,36864,12288,12288,12288,24576,
                              192,192,192,192,192,64,384,3,384,3,1024,64,64};
    const int isb = flag[0];
    int tid0 = blockIdx.x * blockDim.x + threadIdx.x;
    int stride = gridDim.x * blockDim.x;
    for (int j = 0; j < NJ; ++j) {
        const void* s = a.src[j];
        int n = NEL[j];
        if (type[j] == 0) {
            float* d = (float*)a.dst[j];
            for (int i = tid0; i < n; i += stride) d[i] = loadF(s, i, isb);
        } else if (type[j] == 1) {
            float* d = (float*)a.dst[j];
            int K = KD[j];
            for (int i = tid0; i < n; i += stride) {
                int hh = i & 15;
                int k  = (i >> 4) % K;
                int rest = i / (16 * K);      // b*4 + wv
                int wv = rest & 3, b = rest >> 2;
                d[i] = loadF(s, (size_t)(b*64 + wv*16 + hh) * K + k, isb);
            }
        } else if (type[j] == 2) {
            float* d = (float*)a.dst[j];
            int K = KD[j];
            for (int i = tid0; i < n; i += stride) {
                int h = i & 63;
                int k = (i >> 6) % K;
                int b = i / (64 * K);
                d[i] = loadF(s, (size_t)(b*64 + h) * K + k, isb);
            }
        } else {
            unsigned short* d = (unsigned short*)a.dst[j];
            for (int i = tid0; i < n; i += stride) {
                int layer = i / 12288;
                int r1 = i % 12288;
                int c  = r1 / 2048;
                int r2 = r1 % 2048;
                int g  = r2 / 512;
                int r3 = r2 % 512;
                int l  = r3 >> 3;
                int jj = r3 & 7;
                int nn = g * 16 + (l & 15);
                int k  = c * 32 + (l >> 4) * 8 + jj;
                d[i] = f2bf_rtne(loadF(s, (size_t)layer * 12288 + (size_t)nn * 192 + k, isb));
            }
        }
    }
    // zero deg (Nn int) and rel table (Rt*64 bf16 = Rt*32 uint)
    for (int i = tid0; i < Nn; i += stride) degi[i] = 0;
    for (int i = tid0; i < Rt * 32; i += stride) relz[i] = 0u;
}

// ============================ init kernels ============================
__global__ __launch_bounds__(256) void k_count_deg(const int* __restrict__ rowp, int* __restrict__ degi) {
    int e = blockIdx.x * 256 + threadIdx.x;
    if (e < Ee) atomicAdd(&degi[rowp[e]], 1);
}
__global__ __launch_bounds__(256) void k_deg_inv(int* __restrict__ degi) {
    int n = blockIdx.x * 256 + threadIdx.x;
    if (n < Nn) {
        int d = degi[n];
        float r = d > 0 ? 1.0f / sqrtf((float)d) : 0.0f;
        ((float*)degi)[n] = r;
    }
}
__global__ __launch_bounds__(256) void k_node_init(const int* __restrict__ labels,
                                                   const float* __restrict__ posf,
                                                   unsigned short* __restrict__ node) {
    int idx = blockIdx.x * 256 + threadIdx.x;
    if (idx >= Nn * Hh) return;
    int n = idx >> 6, h = idx & 63;
    int pos = labels[2*n] * 4 + labels[2*n + 1];
    node[idx] = f2bf_rtne(posf[pos * 64 + h]);
}
__global__ __launch_bounds__(256) void k_set_rows(const int* __restrict__ positions,
                                                  const float* __restrict__ srcrow,
                                                  unsigned short* __restrict__ node) {
    int idx = blockIdx.x * 256 + threadIdx.x;
    if (idx >= BQ * Hh) return;
    int b = idx >> 6, h = idx & 63;
    node[(size_t)positions[b] * 64 + h] = f2bf_rtne(srcrow[h]);
}
__global__ __launch_bounds__(256) void k_rel_init(const int* __restrict__ qrel,
                                                  const float* __restrict__ srel,
                                                  unsigned short* __restrict__ rel) {
    int idx = blockIdx.x * 256 + threadIdx.x;
    if (idx >= BQ * Hh) return;
    int b = idx >> 6, h = idx & 63;
    rel[((size_t)qrel[b] + (size_t)b * Rr) * 64 + h] = f2bf_rtne(srel[h]);
}
__global__ __launch_bounds__(256) void k_loop_init(const float* __restrict__ l0, float* __restrict__ loop) {
    int idx = blockIdx.x * 256 + threadIdx.x;
    if (idx < BQ * Hh) loop[idx] = l0[idx & 63];
}

// ============================ per-relation alpha/beta factors + zeroing ============================
// a_e = exp(ua[et]+va[eqr]+ba) since W_alpha splits over the concat halves.
// Also zeroes asum/bsum and the bf16 node2/rel2 accumulators for this layer.
__global__ __launch_bounds__(256) void k_uv(const unsigned short* __restrict__ rel,
                                            const float* __restrict__ Wa, const float* __restrict__ Wb,
                                            float* __restrict__ uv,
                                            float* __restrict__ asum,      // asum+bsum contiguous
                                            float4v* __restrict__ node2, float4v* __restrict__ rel2) {
    int tid = threadIdx.x, lane = tid & 63, wv = tid >> 6;
    int w = blockIdx.x * 4 + wv;
    if (w < Rt) {
        float x = bf2f(rel[(size_t)w * 64 + lane]);
        float ax = actf(x);
        float pua = ax * Wa[lane], pva = ax * Wa[64 + lane];
        float pub = x * Wb[lane],  pvb = x * Wb[64 + lane];
        for (int off = 32; off; off >>= 1) {
            pua += __shfl_xor(pua, off); pva += __shfl_xor(pva, off);
            pub += __shfl_xor(pub, off); pvb += __shfl_xor(pvb, off);
        }
        if (lane == 0) {
            uv[w] = pua; uv[Rt + w] = pva; uv[2 * Rt + w] = pub; uv[3 * Rt + w] = pvb;
        }
    }
    // grid-stride zeroing (bf16 accumulators: Nn*64*2 B and Rt*64*2 B)
    int tid0 = blockIdx.x * 256 + tid;
    int stride = gridDim.x * 256;
    float4v z = {0.f, 0.f, 0.f, 0.f};
    for (int i = tid0; i < Nn + Rt; i += stride) asum[i] = 0.f;
    for (int i = tid0; i < Nn * 8; i += stride) node2[i] = z;
    for (int i = tid0; i < Rt * 8; i += stride) rel2[i] = z;
}

__global__ __launch_bounds__(256) void k_ab_edge(const int* __restrict__ et, const int* __restrict__ eqr,
                                                 const int* __restrict__ rowp,
                                                 const float* __restrict__ uv,
                                                 const float* __restrict__ ba, const float* __restrict__ bb,
                                                 float* __restrict__ a_vals, float* __restrict__ b_vals,
                                                 float* __restrict__ a_sum, float* __restrict__ b_sum) {
    int e = blockIdx.x * 256 + threadIdx.x;
    if (e >= Ee) return;
    int t = et[e], q = eqr[e];
    float av = expf(uv[t] + uv[Rt + q] + ba[0]);
    float bv = expf(uv[2 * Rt + t] + uv[3 * Rt + q] + bb[0]);
    a_vals[e] = av; b_vals[e] = bv;
    atomAddF(&a_sum[rowp[e]], av);
    atomAddF(&b_sum[t], bv);
}

// ============================ MFMA edge message kernel ============================
// Block = 64 edges, 4 waves. feat (64 x 192 bf16) gathered into LDS (pitch 200)
// with dwordx4 loads (8 lanes/row, 1 KB/instruction). Weights pre-packed in
// B-fragment registers. Epilogue pairs adjacent columns via shfl and issues
// packed-bf16 atomics (half the atomic ops of fp32 scatter).
template<int KIND>   // 0 = msg1 (h/r/q, dst=node_new[row]), 1 = msg2 (h/t/q, dst=rel_new[et])
__global__ __launch_bounds__(256) void k_msg_mfma(
    const unsigned short* __restrict__ node, const unsigned short* __restrict__ rel,
    const int* __restrict__ col, const int* __restrict__ rowp,
    const int* __restrict__ et, const int* __restrict__ eqr,
    const unsigned short* __restrict__ Wfrag,   // [6][4][64][8] bf16 (this layer)
    const float* __restrict__ bias,             // [64] fp32
    const float* __restrict__ vals, const float* __restrict__ sums,
    const float* __restrict__ deg_inv,          // KIND==0 only
    unsigned short* __restrict__ dst)           // bf16 accumulator table
{
    constexpr int P = 200;                       // bf16 pitch (400 B rows, 16B-aligned)
    __shared__ __align__(16) unsigned short feat[64 * P];
    __shared__ int s_src0[64], s_src1[64], s_src2[64], s_dst[64];
    __shared__ float s_coeff[64];
    const int tid = threadIdx.x;
    const int lane = tid & 63;
    const int wv = tid >> 6;
    const int e0 = blockIdx.x * 64;

    if (tid < 64) {
        int e = e0 + tid;
        int c = col[e], r = rowp[e], t = et[e], q = eqr[e];
        if (KIND == 0) {
            s_src0[tid] = c; s_src1[tid] = t; s_src2[tid] = q; s_dst[tid] = r;
            int rr = rowp[r];                               // faithful double index
            float dn = deg_inv[r] * deg_inv[c];
            s_coeff[tid] = vals[e] / (sums[rr] + 1e-10f) * dn * dn;   // ent_norm twice
        } else {
            s_src0[tid] = c; s_src1[tid] = r; s_src2[tid] = q; s_dst[tid] = t;
            int tt = et[t];                                 // faithful double index
            s_coeff[tid] = vals[e] / (sums[tt] + 1e-10f);
        }
    }

    // B fragments for this wave's 32 output cols
    const int wr = wv >> 1, wc = wv & 1;
    short8v bf[2][6];
#pragma unroll
    for (int tc = 0; tc < 2; ++tc) {
        int g = wc * 2 + tc;
#pragma unroll
        for (int c = 0; c < 6; ++c)
            bf[tc][c] = *(const short8v*)(Wfrag + (((size_t)c * 4 + g) * 64 + lane) * 8);
    }
    __syncthreads();

    // ---- stage: gather 192 bf16 rows (64 edges x 3 parts), 128 B each,
    //      8 lanes per row x 16 B dwordx4 ----
    {
        const int sub = lane >> 3, ls8 = lane & 7;
#pragma unroll
        for (int t2 = 0; t2 < 6; ++t2) {
            int unit = wv * 48 + t2 * 8 + sub;      // unit = part*64 + e
            int e = unit & 63, part = unit >> 6;
            int srow = part == 0 ? s_src0[e] : (part == 1 ? s_src1[e] : s_src2[e]);
            const unsigned short* base;
            if (KIND == 0) base = (part == 0) ? node : rel;
            else           base = (part == 2) ? rel : node;
            uint4 v = *(const uint4*)(base + (size_t)srow * 64 + ls8 * 8);
            *(uint4*)(feat + (size_t)e * P + part * 64 + ls8 * 8) = v;
        }
    }
    __syncthreads();

    // ---- MFMA: 6 K-chunks x 4 tiles ----
    const int m = lane & 15, qd = lane >> 4;
    float4v zero = {0.f, 0.f, 0.f, 0.f};
    float4v acc[2][2];
    acc[0][0] = zero; acc[0][1] = zero; acc[1][0] = zero; acc[1][1] = zero;
#pragma unroll
    for (int c = 0; c < 6; ++c) {
        short8v a0 = *(const short8v*)(feat + (wr * 32 + m) * P + c * 32 + qd * 8);
        short8v a1 = *(const short8v*)(feat + (wr * 32 + 16 + m) * P + c * 32 + qd * 8);
        acc[0][0] = __builtin_amdgcn_mfma_f32_16x16x32_bf16(a0, bf[0][c], acc[0][0], 0, 0, 0);
        acc[0][1] = __builtin_amdgcn_mfma_f32_16x16x32_bf16(a0, bf[1][c], acc[0][1], 0, 0, 0);
        acc[1][0] = __builtin_amdgcn_mfma_f32_16x16x32_bf16(a1, bf[0][c], acc[1][0], 0, 0, 0);
        acc[1][1] = __builtin_amdgcn_mfma_f32_16x16x32_bf16(a1, bf[1][c], acc[1][1], 0, 0, 0);
    }

    // ---- epilogue: act+bias, coeff scale, shfl-pair, packed-bf16 atomics ----
#pragma unroll
    for (int tc = 0; tc < 2; ++tc) {
        int h = wc * 32 + tc * 16 + m;              // C/D: col = lane&15
        float bi = bias[h];
#pragma unroll
        for (int tr = 0; tr < 2; ++tr) {
#pragma unroll
            for (int r = 0; r < 4; ++r) {           // C/D: row = (lane>>4)*4 + reg
                int er = wr * 32 + tr * 16 + qd * 4 + r;
                float v = actf(acc[tr][tc][r] + bi) * s_coeff[er];
                float vn = __shfl_xor(v, 1);        // neighbor holds column h+1
                if (!(lane & 1)) {
                    unsigned int pk = (unsigned int)f2bf_rtne(v)
                                    | ((unsigned int)f2bf_rtne(vn) << 16);
                    atomPkAddBf16(dst + (size_t)s_dst[er] * 64 + h, pk);
                }
            }
        }
    }
#if defined(__HIP_DEVICE_COMPILE__)
    asm volatile("s_waitcnt vmcnt(0)" ::: "memory");   // drain asm atomics before endpgm
#endif
}

// ============================ row-wise 64x64 transform + LN ============================
__global__ __launch_bounds__(256) void k_ent_ln(const unsigned short* __restrict__ x, // node_new bf16
                                                const float* __restrict__ Wv,   // [4][64][16]
                                                const float* __restrict__ bias,
                                                unsigned short* __restrict__ out) { // node_emb bf16
    __shared__ float xT[64 * 65];
    int tid = threadIdx.x, lane = tid & 63;
    int wv = tid >> 6;
    size_t n0 = (size_t)blockIdx.x * 64;
    for (int j = wv; j < 64; j += 4) xT[lane * 65 + j] = bf2f(x[(n0 + j) * 64 + lane]);
    __syncthreads();
    float acc[16];
#pragma unroll
    for (int h = 0; h < 16; ++h) acc[h] = 0.f;
    const float* Wl = Wv + wv * (64 * 16);
    for (int k = 0; k < 64; ++k) {
        float f = xT[k * 65 + lane];
        const float* wr = Wl + k * 16;
#pragma unroll
        for (int hh = 0; hh < 16; ++hh) acc[hh] = fmaf(f, wr[hh], acc[hh]);
    }
    __syncthreads();
    float* yT = xT;
#pragma unroll
    for (int hh = 0; hh < 16; ++hh) {
        int h = wv * 16 + hh;
        yT[h * 65 + lane] = actf(acc[hh] + bias[h]);
    }
    __syncthreads();
    for (int jj = 0; jj < 16; ++jj) {
        int j = wv * 16 + jj;
        float v = yT[lane * 65 + j];
        float s = v, s2 = v * v;
        for (int off = 32; off; off >>= 1) { s += __shfl_xor(s, off); s2 += __shfl_xor(s2, off); }
        float mean = s * (1.f / 64.f);
        float var = s2 * (1.f / 64.f) - mean * mean;
        if (var < 0.f) var = 0.f;
        out[(n0 + j) * 64 + lane] = f2bf_rtne((v - mean) / sqrtf(var + EPS_LN));
    }
}

__global__ __launch_bounds__(256) void k_rel_ln(const unsigned short* __restrict__ x, // rel_new bf16
                                                const float* __restrict__ Wv, const float* __restrict__ bias,
                                                unsigned short* __restrict__ rel,  // bf16, in-place update
                                                float* __restrict__ fin_i) {       // finals[i] fp32
    __shared__ float xT[64 * 65];
    int tid = threadIdx.x, lane = tid & 63;
    int wv = tid >> 6;
    size_t r0 = (size_t)blockIdx.x * 64;
    for (int j = wv; j < 64; j += 4) xT[lane * 65 + j] = bf2f(x[(r0 + j) * 64 + lane]);
    __syncthreads();
    float acc[16];
#pragma unroll
    for (int h = 0; h < 16; ++h) acc[h] = 0.f;
    const float* Wl = Wv + wv * (64 * 16);
    for (int k = 0; k < 64; ++k) {
        float f = xT[k * 65 + lane];
        const float* wr = Wl + k * 16;
#pragma unroll
        for (int hh = 0; hh < 16; ++hh) acc[hh] = fmaf(f, wr[hh], acc[hh]);
    }
    __syncthreads();
    float* yT = xT;
#pragma unroll
    for (int hh = 0; hh < 16; ++hh) {
        int h = wv * 16 + hh;
        yT[h * 65 + lane] = actf(acc[hh] + bias[h]);
    }
    __syncthreads();
    for (int jj = 0; jj < 16; ++jj) {
        int j = wv * 16 + jj;
        float v = yT[lane * 65 + j] + bf2f(rel[(r0 + j) * 64 + lane]);   // residual
        float s = v, s2 = v * v;
        for (int off = 32; off; off >>= 1) { s += __shfl_xor(s, off); s2 += __shfl_xor(s2, off); }
        float mean = s * (1.f / 64.f);
        float var = s2 * (1.f / 64.f) - mean * mean;
        if (var < 0.f) var = 0.f;
        float nv = (v - mean) / sqrtf(var + EPS_LN);
        rel[(r0 + j) * 64 + lane] = f2bf_rtne(nv);
        fin_i[(r0 + j) * 64 + lane] = nv;
    }
}

__global__ __launch_bounds__(64) void k_loop_upd(const unsigned short* __restrict__ rel,
                                                 const int* __restrict__ qrel,
                                                 const float* __restrict__ Wt,   // [128][64] plain transposed
                                                 const float* __restrict__ bias,
                                                 float* __restrict__ loop) {
    __shared__ float cat[128];
    int b = blockIdx.x, lane = threadIdx.x;
    float lv = loop[b * 64 + lane];
    int qr = qrel[b] + b * Rr;
    cat[lane] = lv;
    cat[64 + lane] = bf2f(rel[(size_t)qr * 64 + lane]);
    __syncthreads();
    float acc = 0.f;
    for (int k = 0; k < 128; ++k) acc = fmaf(cat[k], Wt[k * 64 + lane], acc);
    float v = lv + actf(acc + bias[lane]);
    float s = v, s2 = v * v;
    for (int off = 32; off; off >>= 1) { s += __shfl_xor(s, off); s2 += __shfl_xor(s2, off); }
    float mean = s * (1.f / 64.f);
    float var = s2 * (1.f / 64.f) - mean * mean;
    if (var < 0.f) var = 0.f;
    loop[b * 64 + lane] = (v - mean) / sqrtf(var + EPS_LN);
}

// ============================ final projection + LN ============================
__global__ __launch_bounds__(256) void k_final(const float* __restrict__ finals,  // [3][Rt][64]
                                               const float* __restrict__ Wv,      // [4][192][16]
                                               const float* __restrict__ bias,
                                               float* __restrict__ fin_ln) {
    __shared__ float featT[192 * 65];
    int tid = threadIdx.x, lane = tid & 63;
    int wv = tid >> 6;
    size_t r0 = (size_t)blockIdx.x * 64;
    for (int j = wv; j < 192; j += 4) {
        int e = j / 3, part = j - e * 3;
        featT[(part * 64 + lane) * 65 + e] = finals[(size_t)part * Rt * 64 + (r0 + e) * 64 + lane];
    }
    __syncthreads();
    float acc[16];
#pragma unroll
    for (int h = 0; h < 16; ++h) acc[h] = 0.f;
    const float* Wl = Wv + wv * (192 * 16);
    for (int k = 0; k < 192; ++k) {
        float f = featT[k * 65 + lane];
        const float* wr = Wl + k * 16;
#pragma unroll
        for (int hh = 0; hh < 16; ++hh) acc[hh] = fmaf(f, wr[hh], acc[hh]);
    }
    __syncthreads();
    float* yT = featT;
#pragma unroll
    for (int hh = 0; hh < 16; ++hh) {
        int h = wv * 16 + hh;
        yT[h * 65 + lane] = actf(acc[hh] + bias[h]);
    }
    __syncthreads();
    for (int jj = 0; jj < 16; ++jj) {
        int j = wv * 16 + jj;
        float v = yT[lane * 65 + j];
        float s = v, s2 = v * v;
        for (int off = 32; off; off >>= 1) { s += __shfl_xor(s, off); s2 += __shfl_xor(s2, off); }
        float mean = s * (1.f / 64.f);
        float var = s2 * (1.f / 64.f) - mean * mean;
        if (var < 0.f) var = 0.f;
        fin_ln[(r0 + j) * 64 + lane] = (v - mean) / sqrtf(var + EPS_LN);
    }
}

__global__ __launch_bounds__(256) void k_out(const float* __restrict__ fin_ln,
                                             const float* __restrict__ loop,
                                             void* __restrict__ out, int n,
                                             const int* __restrict__ flag) {
    int idx = blockIdx.x * 256 + threadIdx.x;
    if (idx >= n) return;
    int h = idx & 63;
    int j = (idx >> 6) % (Rr + 1);
    int g = idx / ((Rr + 1) * 64);
    float v = 0.f;
    if (j < Rr) {
        for (int s = 0; s < SHOT; ++s)
            v += fin_ln[(size_t)((g * SHOT + s) * Rr + j) * 64 + h];
    } else {
        for (int s = 0; s < SHOT; ++s)
            v += loop[(g * SHOT + s) * 64 + h];
    }
    v *= (1.0f / SHOT);
    if (flag[0]) ((__hip_bfloat16*)out)[idx] = __float2bfloat16(v);
    else         ((float*)out)[idx] = v;
}

// ============================ host launch ============================
extern "C" void kernel_launch(void* const* d_in, const int* in_sizes, int n_in,
                              void* d_out, int out_size, void* d_ws, size_t ws_size,
                              hipStream_t stream) {
    // sentinel guards: absmax ~123 => ws too small; ~77 => wrong input count
    if (ws_size < off_end * 4 || n_in != 29) {
        k_fill16<<<(out_size + 255) / 256, 256, 0, stream>>>(
            (unsigned short*)d_out, out_size, (n_in != 29) ? (unsigned short)0x429A : (unsigned short)0x42F6);
        return;
    }

    const int* edge_index = (const int*)d_in[0];
    const int* col  = edge_index;          // edge_index[0] (h side)
    const int* rowp = edge_index + Ee;     // edge_index[1] (t side)
    const int* et   = (const int*)d_in[1];
    const int* eqr  = (const int*)d_in[2];
    const int* hpos = (const int*)d_in[3];
    const int* tpos = (const int*)d_in[4];
    const int* qrel = (const int*)d_in[5];
    const int* labels = (const int*)d_in[6];

    float* W = (float*)d_ws;
    int*   flag  = (int*)d_ws;             // ws[0]
    unsigned short* node  = (unsigned short*)(W + off_node);
    unsigned short* node2 = (unsigned short*)(W + off_node2);   // bf16 accumulator
    unsigned short* rel   = (unsigned short*)(W + off_rel);
    unsigned short* rel2  = (unsigned short*)(W + off_rel2);    // bf16 accumulator
    float* fin   = W + off_fin;
    float* finln = W + off_finln;
    float* loop  = W + off_loop;
    float* av    = W + off_av;
    float* bvv   = W + off_bvv;
    float* asum  = W + off_asum;
    float* bsum  = W + off_bsum;
    float* deg   = W + off_deg;
    float* uv    = W + off_uv;
    unsigned short* WmsgF  = (unsigned short*)(W + off_WmsgF);
    unsigned short* Wht2rF = (unsigned short*)(W + off_Wht2rF);

    // --- dtype sniff then weight prep (prep also zeroes deg + rel table) ---
    k_sniff<<<1, 64, 0, stream>>>((const unsigned short*)d_in[10], flag);
    PrepArgs pa;
    const int src_idx[19] = {13,15,23,25,27,21, 14,16,24,26,22,28,17,18,19,20,10,11,12};
    void* dsts[19] = {WmsgF, Wht2rF, W+off_Went, W+off_Wrel, W+off_Wfin, W+off_Wloop,
                      W+off_bmsg, W+off_bht2r, W+off_bent, W+off_brel, W+off_bloop, W+off_bfin,
                      W+off_Wa, W+off_ba, W+off_Wb, W+off_bb, W+off_pos, W+off_srel, W+off_loop0};
    for (int j = 0; j < 19; ++j) { pa.src[j] = d_in[src_idx[j]]; pa.dst[j] = dsts[j]; }
    k_prep<<<144, 256, 0, stream>>>(pa, flag, (int*)deg, (unsigned int*)rel);

    // --- degree / init ---
    k_count_deg<<<Ee / 256, 256, 0, stream>>>(rowp, (int*)deg);
    k_deg_inv<<<Nn / 256, 256, 0, stream>>>((int*)deg);
    k_node_init<<<(Nn * Hh) / 256, 256, 0, stream>>>(labels, W + off_pos, node);
    k_set_rows<<<(BQ * Hh + 255) / 256, 256, 0, stream>>>(hpos, W + off_pos, node);        // pos_emb[0]
    k_set_rows<<<(BQ * Hh + 255) / 256, 256, 0, stream>>>(tpos, W + off_pos + 64, node);   // pos_emb[1]
    k_rel_init<<<(BQ * Hh + 255) / 256, 256, 0, stream>>>(qrel, W + off_srel, rel);
    k_loop_init<<<(BQ * Hh + 255) / 256, 256, 0, stream>>>(W + off_loop0, loop);

    // --- layers ---
    for (int i = 0; i < 3; ++i) {
        k_uv<<<2048, 256, 0, stream>>>(rel, W + off_Wa + i * 128, W + off_Wb + i * 128,
                                       uv, asum, (float4v*)node2, (float4v*)rel2);
        k_ab_edge<<<Ee / 256, 256, 0, stream>>>(et, eqr, rowp, uv,
                                                W + off_ba + i, W + off_bb + i,
                                                av, bvv, asum, bsum);
        k_msg_mfma<0><<<Ee / 64, 256, 0, stream>>>(node, rel, col, rowp, et, eqr,
                                                   WmsgF + (size_t)i * 12288, W + off_bmsg + i * 64,
                                                   av, asum, deg, node2);
        k_ent_ln<<<Nn / 64, 256, 0, stream>>>(node2, W + off_Went + (size_t)i * 4096,
                                              W + off_bent + i * 64, node);
        k_msg_mfma<1><<<Ee / 64, 256, 0, stream>>>(node, rel, col, rowp, et, eqr,
                                                   Wht2rF + (size_t)i * 12288, W + off_bht2r + i * 64,
                                                   bvv, bsum, deg, rel2);
        k_rel_ln<<<Rt / 64, 256, 0, stream>>>(rel2, W + off_Wrel + (size_t)i * 4096,
                                              W + off_brel + i * 64, rel, fin + (size_t)i * Rt * Hh);
        k_loop_upd<<<BQ, 64, 0, stream>>>(rel, qrel, W + off_Wloop + (size_t)i * 8192,
                                          W + off_bloop + i * 64, loop);
    }

    // --- final projection, LN, shot-mean, output ---
    k_final<<<Rt / 64, 256, 0, stream>>>(fin, W + off_Wfin, W + off_bfin, finln);
    k_out<<<(out_size + 255) / 256, 256, 0, stream>>>(finln, loop, d_out, out_size, flag);
}